// Round 2
// baseline (45302.066 us; speedup 1.0000x reference)
//
#include <hip/hip_runtime.h>
#include <hip/hip_bf16.h>
#include <math.h>

// ---------------- constants ----------------
#define EMBED 1536
#define HEADS 24
#define HD 64
#define FFN 6144
#define NTOK 257          // sequence length (spatial)
#define BT 64             // b*t
#define TT 8              // frames
#define BV 8              // videos
#define TOK (NTOK*BT)     // 16448 token rows
#define DA 384            // adapter hidden
#define NRD 964

__device__ __forceinline__ float gelu_f(float x){
    return 0.5f * x * (1.0f + erff(x * 0.7071067811865476f));
}

// ---------------- LayerNorm: one block per row ----------------
__global__ __launch_bounds__(256) void ln_kernel(const float* __restrict__ in, float* __restrict__ out,
                                                 const float* __restrict__ w, const float* __restrict__ b, int D){
    __shared__ float shs[4], shss[4];
    const int row = blockIdx.x;
    const float* xr = in + (size_t)row * D;
    float s = 0.f, ss = 0.f;
    for (int i = threadIdx.x * 4; i < D; i += 1024){
        float4 v = *(const float4*)&xr[i];
        s  += v.x + v.y + v.z + v.w;
        ss += v.x*v.x + v.y*v.y + v.z*v.z + v.w*v.w;
    }
    #pragma unroll
    for (int off = 32; off >= 1; off >>= 1){ s += __shfl_down(s, off); ss += __shfl_down(ss, off); }
    const int wid = threadIdx.x >> 6;
    if ((threadIdx.x & 63) == 0){ shs[wid] = s; shss[wid] = ss; }
    __syncthreads();
    s  = shs[0] + shs[1] + shs[2] + shs[3];
    ss = shss[0] + shss[1] + shss[2] + shss[3];
    const float mu  = s / D;
    const float var = ss / D - mu * mu;
    const float inv = rsqrtf(var + 1e-5f);
    float* orow = out + (size_t)row * D;
    for (int i = threadIdx.x * 4; i < D; i += 1024){
        float4 v = *(const float4*)&xr[i];
        float4 wv = *(const float4*)&w[i];
        float4 bv = *(const float4*)&b[i];
        float4 r;
        r.x = (v.x - mu) * inv * wv.x + bv.x;
        r.y = (v.y - mu) * inv * wv.y + bv.y;
        r.z = (v.z - mu) * inv * wv.z + bv.z;
        r.w = (v.w - mu) * inv * wv.w + bv.w;
        *(float4*)&orow[i] = r;
    }
}

// ---------------- generic fp32 GEMM, 64x64 tile, fused epilogue ----------------
// C[r][c] = (acc + bias[c]) * scale -> gelu? -> *colscale[c] -> + addend[r][c]
__global__ __launch_bounds__(256) void gemm_kernel(
    const float* __restrict__ A, const float* __restrict__ B, float* __restrict__ C,
    int M, int K, int Nc,
    const float* __restrict__ bias, float scale, int do_gelu,
    const float* __restrict__ colscale, const float* __restrict__ addend)
{
    __shared__ float As[16][64];
    __shared__ float Bs[16][64];
    const int tid = threadIdx.x;
    const int row0 = blockIdx.y * 64, col0 = blockIdx.x * 64;
    const int tm = tid >> 4, tn = tid & 15;
    const int la_m = tid >> 2, la_k = (tid & 3) * 4;
    const int lb_k = tid >> 4, lb_n = (tid & 15) * 4;
    float acc[4][4] = {};
    const float* Aptr = A + (size_t)(row0 + la_m) * K + la_k;
    const float* Bptr = B + (size_t)lb_k * Nc + col0 + lb_n;
    for (int k0 = 0; k0 < K; k0 += 16){
        float4 a4 = *(const float4*)(Aptr + k0);
        float4 b4 = *(const float4*)(Bptr + (size_t)k0 * Nc);
        As[la_k + 0][la_m] = a4.x;
        As[la_k + 1][la_m] = a4.y;
        As[la_k + 2][la_m] = a4.z;
        As[la_k + 3][la_m] = a4.w;
        *(float4*)&Bs[lb_k][lb_n] = b4;
        __syncthreads();
        #pragma unroll
        for (int kk = 0; kk < 16; ++kk){
            float4 av = *(const float4*)&As[kk][tm * 4];
            float4 bv = *(const float4*)&Bs[kk][tn * 4];
            float a_[4] = {av.x, av.y, av.z, av.w};
            float b_[4] = {bv.x, bv.y, bv.z, bv.w};
            #pragma unroll
            for (int i = 0; i < 4; ++i)
                #pragma unroll
                for (int j = 0; j < 4; ++j)
                    acc[i][j] = fmaf(a_[i], b_[j], acc[i][j]);
        }
        __syncthreads();
    }
    #pragma unroll
    for (int i = 0; i < 4; ++i){
        const int r = row0 + tm * 4 + i;
        float* orow = C + (size_t)r * Nc + col0 + tn * 4;
        const float* arow = addend ? (addend + (size_t)r * Nc + col0 + tn * 4) : nullptr;
        float4 o;
        #pragma unroll
        for (int j = 0; j < 4; ++j){
            const int c = col0 + tn * 4 + j;
            float v = acc[i][j];
            if (bias) v += bias[c];
            v *= scale;
            if (do_gelu) v = gelu_f(v);
            if (colscale) v *= colscale[c];
            if (arow) v += arow[j];
            (&o.x)[j] = v;
        }
        *(float4*)orow = o;
    }
}

// ---------------- temporal attention: L=8 over frames, in-place into q ----------------
// token row r(n, b, t) = n*64 + b*8 + t ;  head h slice [h*64, h*64+64)
__global__ __launch_bounds__(64) void attn_temporal_kernel(
    float* __restrict__ q, const float* __restrict__ k, const float* __restrict__ v)
{
    const int h = blockIdx.x, n = blockIdx.y, b = blockIdx.z;
    const int d = threadIdx.x;
    __shared__ float qs[8][64], ks[8][64], vs[8][64];
    __shared__ float sc[8][8], pr[8][8];
    #pragma unroll
    for (int t = 0; t < 8; ++t){
        size_t r = ((size_t)n * 64 + b * 8 + t) * EMBED + h * 64 + d;
        qs[t][d] = q[r]; ks[t][d] = k[r]; vs[t][d] = v[r];
    }
    __syncthreads();
    {
        const int qi = d >> 3, kj = d & 7;
        float s = 0.f;
        #pragma unroll
        for (int e = 0; e < 64; ++e) s = fmaf(qs[qi][e], ks[kj][e], s);
        sc[qi][kj] = s;
    }
    __syncthreads();
    if (d < 8){
        float m = -3.4e38f;
        #pragma unroll
        for (int j = 0; j < 8; ++j) m = fmaxf(m, sc[d][j]);
        float sum = 0.f;
        #pragma unroll
        for (int j = 0; j < 8; ++j){ float e = expf(sc[d][j] - m); pr[d][j] = e; sum += e; }
        const float inv = 1.f / sum;
        #pragma unroll
        for (int j = 0; j < 8; ++j) pr[d][j] *= inv;
    }
    __syncthreads();
    #pragma unroll
    for (int qi = 0; qi < 8; ++qi){
        float o = 0.f;
        #pragma unroll
        for (int t = 0; t < 8; ++t) o = fmaf(pr[qi][t], vs[t][d], o);
        q[((size_t)n * 64 + b * 8 + qi) * EMBED + h * 64 + d] = o;
    }
}

// ---------------- spatial attention: one block per (query n, bt, head), in-place into q ----------------
__global__ __launch_bounds__(256) void attn_spatial_kernel(
    float* __restrict__ q, const float* __restrict__ k, const float* __restrict__ v,
    const float* __restrict__ bias)
{
    const int nq = blockIdx.x, bt = blockIdx.y, h = blockIdx.z;
    __shared__ float qsh[64];
    __shared__ float s[NTOK];
    __shared__ float part[4][64];
    __shared__ float redm[4], reds[4];
    const int tid = threadIdx.x;
    if (tid < 64) qsh[tid] = q[((size_t)nq * 64 + bt) * EMBED + h * 64 + tid];
    __syncthreads();
    float lmax = -3.4e38f;
    for (int j = tid; j < NTOK; j += 256){
        const float* kr = &k[((size_t)j * 64 + bt) * EMBED + h * 64];
        float acc = 0.f;
        #pragma unroll
        for (int e = 0; e < 64; ++e) acc = fmaf(qsh[e], kr[e], acc);
        acc += bias[(size_t)h * (NTOK * NTOK) + (size_t)nq * NTOK + j];
        s[j] = acc;
        lmax = fmaxf(lmax, acc);
    }
    #pragma unroll
    for (int off = 32; off >= 1; off >>= 1) lmax = fmaxf(lmax, __shfl_down(lmax, off));
    const int wid = tid >> 6;
    if ((tid & 63) == 0) redm[wid] = lmax;
    __syncthreads();
    lmax = fmaxf(fmaxf(redm[0], redm[1]), fmaxf(redm[2], redm[3]));
    float lsum = 0.f;
    for (int j = tid; j < NTOK; j += 256){
        float e = expf(s[j] - lmax);
        s[j] = e;
        lsum += e;
    }
    #pragma unroll
    for (int off = 32; off >= 1; off >>= 1) lsum += __shfl_down(lsum, off);
    if ((tid & 63) == 0) reds[wid] = lsum;
    __syncthreads();   // also makes all s[] writes visible
    const float inv = 1.f / (reds[0] + reds[1] + reds[2] + reds[3]);
    const int d = tid & 63, g = tid >> 6;
    float o = 0.f;
    for (int j = g; j < NTOK; j += 4)
        o = fmaf(s[j], v[((size_t)j * 64 + bt) * EMBED + h * 64 + d], o);
    part[g][d] = o;
    __syncthreads();
    if (tid < 64)
        q[((size_t)nq * 64 + bt) * EMBED + h * 64 + tid] =
            (part[0][tid] + part[1][tid] + part[2][tid] + part[3][tid]) * inv;
}

// ---------------- relative-position bias gather: bias[h][i][j] ----------------
__global__ void bias_gather_kernel(const float* __restrict__ rpw, const int* __restrict__ bucket,
                                   float* __restrict__ bias){
    const int i = blockIdx.x * 256 + threadIdx.x;
    const int total = HEADS * NTOK * NTOK;
    if (i < total){
        const int h = i / (NTOK * NTOK);
        const int ij = i % (NTOK * NTOK);
        bias[i] = rpw[(size_t)bucket[ij] * HEADS + h];
    }
}

// ---------------- elementwise: o = a + g[c]*b ----------------
__global__ void add_scaled_kernel(const float* __restrict__ a, const float* __restrict__ g,
                                  const float* __restrict__ bsrc, float* __restrict__ o, size_t n){
    size_t i = (size_t)blockIdx.x * blockDim.x + threadIdx.x;
    if (i < n){
        int c = (int)(i % EMBED);
        o[i] = a[i] + g[c] * bsrc[i];
    }
}

// ---------------- elementwise: h0 = gelu(h0)*h1 ----------------
__global__ void gate_kernel(float* __restrict__ h0, const float* __restrict__ h1, size_t n){
    size_t i = (size_t)blockIdx.x * blockDim.x + threadIdx.x;
    if (i < n) h0[i] = gelu_f(h0[i]) * h1[i];
}

// ---------------- host-side helpers ----------------
static inline void run_gemm(const float* A, const float* B, float* C, int M, int K, int Nc,
                            const float* bias, float scale, int do_gelu,
                            const float* colscale, const float* addend, hipStream_t stream){
    dim3 grid(Nc / 64, M / 64);
    gemm_kernel<<<grid, 256, 0, stream>>>(A, B, C, M, K, Nc, bias, scale, do_gelu, colscale, addend);
}

extern "C" void kernel_launch(void* const* d_in, const int* in_sizes, int n_in,
                              void* d_out, int out_size, void* d_ws, size_t ws_size,
                              hipStream_t stream){
    const float* x        = (const float*)d_in[0];
    const float* q_w      = (const float*)d_in[1];
    const float* k_w      = (const float*)d_in[2];
    const float* v_w      = (const float*)d_in[3];
    const float* out_w    = (const float*)d_in[4];
    const float* q_b      = (const float*)d_in[5];
    const float* v_b      = (const float*)d_in[6];
    const float* out_b    = (const float*)d_in[7];
    const float* attn_ln_w= (const float*)d_in[8];
    const float* attn_ln_b= (const float*)d_in[9];
    const float* sa_ln_w  = (const float*)d_in[10];
    const float* sa_ln_b  = (const float*)d_in[11];
    const float* fin_ln_w = (const float*)d_in[12];
    const float* fin_ln_b = (const float*)d_in[13];
    const float* wi0      = (const float*)d_in[14];
    const float* wi1      = (const float*)d_in[15];
    const float* ffn_ln_w = (const float*)d_in[16];
    const float* ffn_ln_b = (const float*)d_in[17];
    const float* ffn_out_w= (const float*)d_in[18];
    const float* ffn_out_b= (const float*)d_in[19];
    const float* gamma1   = (const float*)d_in[20];
    const float* gamma2   = (const float*)d_in[21];
    const float* t_fc1_w  = (const float*)d_in[22];
    const float* t_fc1_b  = (const float*)d_in[23];
    const float* t_fc2_w  = (const float*)d_in[24];
    const float* t_fc2_b  = (const float*)d_in[25];
    const float* s_fc1_w  = (const float*)d_in[26];
    const float* s_fc1_b  = (const float*)d_in[27];
    const float* s_fc2_w  = (const float*)d_in[28];
    const float* s_fc2_b  = (const float*)d_in[29];
    const float* m_fc1_w  = (const float*)d_in[30];
    const float* m_fc1_b  = (const float*)d_in[31];
    const float* m_fc2_w  = (const float*)d_in[32];
    const float* m_fc2_b  = (const float*)d_in[33];
    const float* rel_pos_w= (const float*)d_in[34];
    const int*   rp_bucket= (const int*)d_in[35];

    float* out = (float*)d_out;           // also used as a full token-sized buffer
    float* ws  = (float*)d_ws;

    const size_t TOKD = (size_t)TOK * EMBED;            // 25,264,128 floats
    const size_t BIASZ = (size_t)HEADS * NTOK * NTOK;   //  1,585,176 floats
    const int CHA = 2048;                               // attention-path row chunk
    const int CHF = 512;                                // FFN-path row chunk

    float* W0   = ws;
    float* W1   = ws + TOKD;
    float* BIAS = ws + 2 * TOKD;
    float* S    = BIAS + BIASZ;                         // shared chunk scratch

    // attention-path scratch layout inside S
    float* Lc   = S;                                    // CHA x EMBED   (3,145,728)
    float* ABa  = S + (size_t)CHA * EMBED;              // CHA x DA      (  786,432)
    // FFN-path scratch layout inside S (CHF rows)
    float* LcF  = S;                                    // CHF x EMBED   (  786,432)
    float* H0   = LcF + (size_t)CHF * EMBED;            // CHF x FFN     (3,145,728)
    float* H1   = H0  + (size_t)CHF * FFN;              // CHF x FFN     (3,145,728)
    float* ABf  = H1  + (size_t)CHF * FFN;              // CHF x DA      (  196,608)
    float* MF   = ABf + (size_t)CHF * DA;               // CHF x EMBED   (  786,432)

    const size_t s_attn = (size_t)CHA * EMBED + (size_t)CHA * DA;
    const size_t s_ffn  = (size_t)CHF * EMBED * 2 + (size_t)CHF * FFN * 2 + (size_t)CHF * DA;
    const size_t s_need = (s_attn > s_ffn) ? s_attn : s_ffn;
    const size_t need = (2 * TOKD + BIASZ + s_need) * sizeof(float);
    if (ws_size < need) return;   // diagnostic: zeros out => ws still too small

    const float qscale = 0.125f;  // HD^-0.5

    // ================= temporal attention =================
    // Q -> out(d_out), K -> W0, V -> W1  (LN chunked so ln output never fully materialized)
    for (int m0 = 0; m0 < TOK; m0 += CHA){
        const int mc = (TOK - m0 < CHA) ? (TOK - m0) : CHA;
        ln_kernel<<<mc, 256, 0, stream>>>(x + (size_t)m0 * EMBED, Lc, sa_ln_w, sa_ln_b, EMBED);
        run_gemm(Lc, q_w, out + (size_t)m0 * EMBED, mc, EMBED, EMBED, q_b, qscale, 0, nullptr, nullptr, stream);
        run_gemm(Lc, k_w, W0  + (size_t)m0 * EMBED, mc, EMBED, EMBED, nullptr, 1.f, 0, nullptr, nullptr, stream);
        run_gemm(Lc, v_w, W1  + (size_t)m0 * EMBED, mc, EMBED, EMBED, v_b, 1.f, 0, nullptr, nullptr, stream);
    }
    attn_temporal_kernel<<<dim3(HEADS, NTOK, BV), 64, 0, stream>>>(out, W0, W1);   // A in-place in d_out
    // inner LN + out_proj -> AO in W0 ; adapter t + residual(x) -> x1 in d_out
    for (int m0 = 0; m0 < TOK; m0 += CHA){
        const int mc = (TOK - m0 < CHA) ? (TOK - m0) : CHA;
        ln_kernel<<<mc, 256, 0, stream>>>(out + (size_t)m0 * EMBED, Lc, attn_ln_w, attn_ln_b, EMBED);
        run_gemm(Lc, out_w, W0 + (size_t)m0 * EMBED, mc, EMBED, EMBED, out_b, 1.f, 0, nullptr, nullptr, stream);
    }
    for (int m0 = 0; m0 < TOK; m0 += CHA){
        const int mc = (TOK - m0 < CHA) ? (TOK - m0) : CHA;
        run_gemm(W0 + (size_t)m0 * EMBED, t_fc1_w, ABa, mc, EMBED, DA, t_fc1_b, 1.f, 1, nullptr, nullptr, stream);
        run_gemm(ABa, t_fc2_w, out + (size_t)m0 * EMBED, mc, DA, EMBED, t_fc2_b, 1.f, 0, nullptr,
                 x + (size_t)m0 * EMBED, stream);
    }

    // ================= spatial attention =================
    // x1 in d_out.  Q -> W0, K -> W1, V -> d_out (in-place over x1, chunk by chunk)
    for (int m0 = 0; m0 < TOK; m0 += CHA){
        const int mc = (TOK - m0 < CHA) ? (TOK - m0) : CHA;
        ln_kernel<<<mc, 256, 0, stream>>>(out + (size_t)m0 * EMBED, Lc, sa_ln_w, sa_ln_b, EMBED);
        run_gemm(Lc, q_w, W0 + (size_t)m0 * EMBED, mc, EMBED, EMBED, q_b, qscale, 0, nullptr, nullptr, stream);
        run_gemm(Lc, k_w, W1 + (size_t)m0 * EMBED, mc, EMBED, EMBED, nullptr, 1.f, 0, nullptr, nullptr, stream);
        run_gemm(Lc, v_w, out + (size_t)m0 * EMBED, mc, EMBED, EMBED, v_b, 1.f, 0, nullptr, nullptr, stream);
    }
    {
        const int total = HEADS * NTOK * NTOK;
        bias_gather_kernel<<<(total + 255) / 256, 256, 0, stream>>>(rel_pos_w, rp_bucket, BIAS);
    }
    attn_spatial_kernel<<<dim3(NTOK, BT, HEADS), 256, 0, stream>>>(W0, W1, out, BIAS);  // A in-place in W0
    // inner LN + out_proj -> aos in W1 ; adapter s (skip) -> xs in W0 ; x2 = x + gamma1*xs -> d_out
    for (int m0 = 0; m0 < TOK; m0 += CHA){
        const int mc = (TOK - m0 < CHA) ? (TOK - m0) : CHA;
        ln_kernel<<<mc, 256, 0, stream>>>(W0 + (size_t)m0 * EMBED, Lc, attn_ln_w, attn_ln_b, EMBED);
        run_gemm(Lc, out_w, W1 + (size_t)m0 * EMBED, mc, EMBED, EMBED, out_b, 1.f, 0, nullptr, nullptr, stream);
    }
    for (int m0 = 0; m0 < TOK; m0 += CHA){
        const int mc = (TOK - m0 < CHA) ? (TOK - m0) : CHA;
        run_gemm(W1 + (size_t)m0 * EMBED, s_fc1_w, ABa, mc, EMBED, DA, s_fc1_b, 1.f, 1, nullptr, nullptr, stream);
        run_gemm(ABa, s_fc2_w, W0 + (size_t)m0 * EMBED, mc, DA, EMBED, s_fc2_b, 1.f, 0, nullptr,
                 W1 + (size_t)m0 * EMBED, stream);
    }
    {
        size_t n = TOKD;
        add_scaled_kernel<<<(unsigned)((n + 255) / 256), 256, 0, stream>>>(x, gamma1, W0, out, n);
    }

    // ================= FFN (GEGLU + inner LN) + adapter m + final combine =================
    // x2 in d_out; everything chunked; d_out overwritten last per chunk.
    for (int m0 = 0; m0 < TOK; m0 += CHF){
        const int mc = (TOK - m0 < CHF) ? (TOK - m0) : CHF;
        float* x2c = out + (size_t)m0 * EMBED;
        ln_kernel<<<mc, 256, 0, stream>>>(x2c, LcF, fin_ln_w, fin_ln_b, EMBED);          // xn chunk
        run_gemm(LcF, wi0, H0, mc, EMBED, FFN, nullptr, 1.f, 0, nullptr, nullptr, stream);
        run_gemm(LcF, wi1, H1, mc, EMBED, FFN, nullptr, 1.f, 0, nullptr, nullptr, stream);
        {
            size_t n = (size_t)mc * FFN;
            gate_kernel<<<(unsigned)((n + 255) / 256), 256, 0, stream>>>(H0, H1, n);
        }
        ln_kernel<<<mc, 256, 0, stream>>>(H0, H1, ffn_ln_w, ffn_ln_b, FFN);
        // adapter m chunk: MF = gelu(xn@m_fc1+b)@m_fc2 + m_fc2_b + x2
        run_gemm(LcF, m_fc1_w, ABf, mc, EMBED, DA, m_fc1_b, 1.f, 1, nullptr, nullptr, stream);
        run_gemm(ABf, m_fc2_w, MF, mc, DA, EMBED, m_fc2_b, 1.f, 0, nullptr, x2c, stream);
        // out chunk = gamma2*(H1@ffn_out_w + ffn_out_b) + (x2 + madapt)
        run_gemm(H1, ffn_out_w, x2c, mc, FFN, EMBED, ffn_out_b, 1.f, 0, gamma2, MF, stream);
    }
}

// Round 3
// 21993.488 us; speedup vs baseline: 2.0598x; 2.0598x over previous
//
#include <hip/hip_runtime.h>
#include <hip/hip_bf16.h>
#include <math.h>

// ---------------- constants ----------------
#define EMBED 1536
#define HEADS 24
#define HD 64
#define FFN 6144
#define NTOK 257          // sequence length (spatial)
#define BT 64             // b*t
#define TT 8              // frames
#define BV 8              // videos
#define TOK (NTOK*BT)     // 16448 token rows
#define DA 384            // adapter hidden
#define NRD 964
#define CHA 2048          // attention-path row chunk
#define CHF 1024          // FFN-path row chunk

typedef __bf16 bf16x8_t __attribute__((ext_vector_type(8)));
typedef float  f32x4    __attribute__((ext_vector_type(4)));

__device__ __forceinline__ float gelu_f(float x){
    return 0.5f * x * (1.0f + erff(x * 0.7071067811865476f));
}
__device__ __forceinline__ float bf2f(ushort u){
    union { uint i; float f; } c; c.i = ((uint)u) << 16; return c.f;
}
__device__ __forceinline__ ushort f2bf(float f){
    union { float f; uint i; } c; c.f = f;
    uint r = (c.i + 0x7fffu + ((c.i >> 16) & 1u)) >> 16;
    return (ushort)r;
}

// ---------------- weight transpose + bf16 convert: w[K][N] -> wt[N][K] ----------------
__global__ __launch_bounds__(256) void transpose_w(const float* __restrict__ w, ushort* __restrict__ wt,
                                                   int K, int N){
    __shared__ float t[32][33];
    const int n0 = blockIdx.x * 32, k0 = blockIdx.y * 32;
    const int tx = threadIdx.x & 31, ty = threadIdx.x >> 5;   // 32 x 8
    #pragma unroll
    for (int i = 0; i < 4; ++i)
        t[ty + 8*i][tx] = w[(size_t)(k0 + ty + 8*i) * N + n0 + tx];
    __syncthreads();
    #pragma unroll
    for (int i = 0; i < 4; ++i)
        wt[(size_t)(n0 + ty + 8*i) * K + k0 + tx] = f2bf(t[tx][ty + 8*i]);
}

// ---------------- LayerNorm (templated input dtype), bf16 output ----------------
template<typename TI>
__global__ __launch_bounds__(256) void ln_kernel(const TI* __restrict__ in, ushort* __restrict__ out,
                                                 const float* __restrict__ w, const float* __restrict__ b, int D){
    __shared__ float shs[4], shss[4];
    const int row = blockIdx.x;
    const TI* xr = in + (size_t)row * D;
    float s = 0.f, ss = 0.f;
    for (int i = threadIdx.x * 8; i < D; i += 2048){
        float vv[8];
        if constexpr (sizeof(TI) == 4){
            float4 a = *(const float4*)&xr[i];
            float4 c = *(const float4*)&xr[i + 4];
            vv[0]=a.x; vv[1]=a.y; vv[2]=a.z; vv[3]=a.w;
            vv[4]=c.x; vv[5]=c.y; vv[6]=c.z; vv[7]=c.w;
        } else {
            int4 u = *(const int4*)&xr[i];
            const ushort* up = (const ushort*)&u;
            #pragma unroll
            for (int j = 0; j < 8; ++j) vv[j] = bf2f(up[j]);
        }
        #pragma unroll
        for (int j = 0; j < 8; ++j){ s += vv[j]; ss += vv[j]*vv[j]; }
    }
    #pragma unroll
    for (int off = 32; off >= 1; off >>= 1){ s += __shfl_down(s, off); ss += __shfl_down(ss, off); }
    const int wid = threadIdx.x >> 6;
    if ((threadIdx.x & 63) == 0){ shs[wid] = s; shss[wid] = ss; }
    __syncthreads();
    s  = shs[0] + shs[1] + shs[2] + shs[3];
    ss = shss[0] + shss[1] + shss[2] + shss[3];
    const float mu  = s / D;
    const float inv = rsqrtf(ss / D - mu * mu + 1e-5f);
    ushort* orow = out + (size_t)row * D;
    for (int i = threadIdx.x * 8; i < D; i += 2048){
        float vv[8];
        if constexpr (sizeof(TI) == 4){
            float4 a = *(const float4*)&xr[i];
            float4 c = *(const float4*)&xr[i + 4];
            vv[0]=a.x; vv[1]=a.y; vv[2]=a.z; vv[3]=a.w;
            vv[4]=c.x; vv[5]=c.y; vv[6]=c.z; vv[7]=c.w;
        } else {
            int4 u = *(const int4*)&xr[i];
            const ushort* up = (const ushort*)&u;
            #pragma unroll
            for (int j = 0; j < 8; ++j) vv[j] = bf2f(up[j]);
        }
        ushort ov[8];
        #pragma unroll
        for (int j = 0; j < 8; ++j)
            ov[j] = f2bf((vv[j] - mu) * inv * w[i + j] + b[i + j]);
        *(int4*)&orow[i] = *(const int4*)ov;
    }
}

// ---------------- fused gate (a*b) + LayerNorm, bf16 in/out ----------------
__global__ __launch_bounds__(256) void lnmul_kernel(const ushort* __restrict__ ina, const ushort* __restrict__ inb,
                                                    ushort* __restrict__ out,
                                                    const float* __restrict__ w, const float* __restrict__ b, int D){
    __shared__ float shs[4], shss[4];
    const int row = blockIdx.x;
    const ushort* ar = ina + (size_t)row * D;
    const ushort* br = inb + (size_t)row * D;
    float s = 0.f, ss = 0.f;
    for (int i = threadIdx.x * 8; i < D; i += 2048){
        int4 ua = *(const int4*)&ar[i];
        int4 ub = *(const int4*)&br[i];
        const ushort* pa = (const ushort*)&ua;
        const ushort* pb = (const ushort*)&ub;
        #pragma unroll
        for (int j = 0; j < 8; ++j){ float v = bf2f(pa[j]) * bf2f(pb[j]); s += v; ss += v*v; }
    }
    #pragma unroll
    for (int off = 32; off >= 1; off >>= 1){ s += __shfl_down(s, off); ss += __shfl_down(ss, off); }
    const int wid = threadIdx.x >> 6;
    if ((threadIdx.x & 63) == 0){ shs[wid] = s; shss[wid] = ss; }
    __syncthreads();
    s  = shs[0] + shs[1] + shs[2] + shs[3];
    ss = shss[0] + shss[1] + shss[2] + shss[3];
    const float mu  = s / D;
    const float inv = rsqrtf(ss / D - mu * mu + 1e-5f);
    ushort* orow = out + (size_t)row * D;
    for (int i = threadIdx.x * 8; i < D; i += 2048){
        int4 ua = *(const int4*)&ar[i];
        int4 ub = *(const int4*)&br[i];
        const ushort* pa = (const ushort*)&ua;
        const ushort* pb = (const ushort*)&ub;
        ushort ov[8];
        #pragma unroll
        for (int j = 0; j < 8; ++j){
            float v = bf2f(pa[j]) * bf2f(pb[j]);
            ov[j] = f2bf((v - mu) * inv * w[i + j] + b[i + j]);
        }
        *(int4*)&orow[i] = *(const int4*)ov;
    }
}

// ---------------- bf16 MFMA GEMM: A[M][K] x Bt[N][K]^T -> C[M][N], fused epilogue ----------------
// v = acc; (+bias[c]); *scale; gelu?; (+= bf16 addb[r][c]); if gvec: v = addf + gvec[c]*v else (+= addf)
__global__ __launch_bounds__(256) void mfma_gemm(
    const ushort* __restrict__ A, const ushort* __restrict__ Bt,
    int M, int N, int K,
    const float* __restrict__ bias, float scale, int dogelu,
    const ushort* __restrict__ addb, const float* __restrict__ addf,
    const float* __restrict__ gvec, void* __restrict__ Cout, int obf16)
{
    __shared__ ushort As[4096];   // 128 rows x 32 k, fragment-subtile order
    __shared__ ushort Bs[4096];
    const int tid  = threadIdx.x;
    const int lane = tid & 63, wave = tid >> 6;
    const int wr = wave >> 1, wc = wave & 1;
    const int row0 = blockIdx.y * 128, col0 = blockIdx.x * 128;

    f32x4 acc[4][4] = {};

    const int crow = tid >> 2;          // 0..63
    const int ckb  = tid & 3;           // k-block of 8
    int ra0 = row0 + crow;       if (ra0 > M-1) ra0 = M-1;
    int ra1 = row0 + crow + 64;  if (ra1 > M-1) ra1 = M-1;
    const int rb0 = col0 + crow;
    const int rb1 = col0 + crow + 64;
    // LDS dst (ushort units): subtile(row>>4)*512 + (kb*16 + row&15)*8
    const int d0 = ((crow >> 4) << 9) + ((ckb << 4) + (crow & 15)) * 8;
    const int d1 = (((crow + 64) >> 4) << 9) + ((ckb << 4) + (crow & 15)) * 8;

    for (int k0 = 0; k0 < K; k0 += 32){
        const int4 a0 = *(const int4*)(A  + (size_t)ra0 * K + k0 + ckb * 8);
        const int4 a1 = *(const int4*)(A  + (size_t)ra1 * K + k0 + ckb * 8);
        const int4 b0 = *(const int4*)(Bt + (size_t)rb0 * K + k0 + ckb * 8);
        const int4 b1 = *(const int4*)(Bt + (size_t)rb1 * K + k0 + ckb * 8);
        __syncthreads();
        *(int4*)&As[d0] = a0; *(int4*)&As[d1] = a1;
        *(int4*)&Bs[d0] = b0; *(int4*)&Bs[d1] = b1;
        __syncthreads();
        bf16x8_t af[4], bfr[4];
        #pragma unroll
        for (int mi = 0; mi < 4; ++mi)
            af[mi] = *(const bf16x8_t*)&As[(((wr<<2)+mi) << 9) + lane * 8];
        #pragma unroll
        for (int ni = 0; ni < 4; ++ni)
            bfr[ni] = *(const bf16x8_t*)&Bs[(((wc<<2)+ni) << 9) + lane * 8];
        #pragma unroll
        for (int mi = 0; mi < 4; ++mi)
            #pragma unroll
            for (int ni = 0; ni < 4; ++ni)
                acc[mi][ni] = __builtin_amdgcn_mfma_f32_16x16x32_bf16(af[mi], bfr[ni], acc[mi][ni], 0, 0, 0);
    }

    const int fr = lane >> 4;   // 0..3
    const int fc = lane & 15;
    #pragma unroll
    for (int mi = 0; mi < 4; ++mi){
        #pragma unroll
        for (int j = 0; j < 4; ++j){
            const int r = row0 + wr*64 + mi*16 + fr*4 + j;
            if (r < M){
                #pragma unroll
                for (int ni = 0; ni < 4; ++ni){
                    const int c = col0 + wc*64 + ni*16 + fc;
                    float v = acc[mi][ni][j];
                    if (bias) v += bias[c];
                    v *= scale;
                    if (dogelu) v = gelu_f(v);
                    if (addb) v += bf2f(addb[(size_t)r*N + c]);
                    if (gvec) v = addf[(size_t)r*N + c] + gvec[c]*v;
                    else if (addf) v += addf[(size_t)r*N + c];
                    if (obf16) ((ushort*)Cout)[(size_t)r*N + c] = f2bf(v);
                    else       ((float*)Cout)[(size_t)r*N + c] = v;
                }
            }
        }
    }
}

// ---------------- temporal attention: L=8 over frames, bf16, in-place into q ----------------
__global__ __launch_bounds__(64) void attn_temporal_kernel(
    ushort* __restrict__ q, const ushort* __restrict__ k, const ushort* __restrict__ v)
{
    const int h = blockIdx.x, n = blockIdx.y, b = blockIdx.z;
    const int d = threadIdx.x;
    __shared__ float qs[8][64], ks[8][64], vs[8][64];
    __shared__ float sc[8][8], pr[8][8];
    #pragma unroll
    for (int t = 0; t < 8; ++t){
        size_t r = ((size_t)n * 64 + b * 8 + t) * EMBED + h * 64 + d;
        qs[t][d] = bf2f(q[r]); ks[t][d] = bf2f(k[r]); vs[t][d] = bf2f(v[r]);
    }
    __syncthreads();
    {
        const int qi = d >> 3, kj = d & 7;
        float s = 0.f;
        #pragma unroll
        for (int e = 0; e < 64; ++e) s = fmaf(qs[qi][e], ks[kj][e], s);
        sc[qi][kj] = s;
    }
    __syncthreads();
    if (d < 8){
        float m = -3.4e38f;
        #pragma unroll
        for (int j = 0; j < 8; ++j) m = fmaxf(m, sc[d][j]);
        float sum = 0.f;
        #pragma unroll
        for (int j = 0; j < 8; ++j){ float e = expf(sc[d][j] - m); pr[d][j] = e; sum += e; }
        const float inv = 1.f / sum;
        #pragma unroll
        for (int j = 0; j < 8; ++j) pr[d][j] *= inv;
    }
    __syncthreads();
    #pragma unroll
    for (int qi = 0; qi < 8; ++qi){
        float o = 0.f;
        #pragma unroll
        for (int t = 0; t < 8; ++t) o = fmaf(pr[qi][t], vs[t][d], o);
        q[((size_t)n * 64 + b * 8 + qi) * EMBED + h * 64 + d] = f2bf(o);
    }
}

// ---------------- spatial attention: one block per (query n, bt, head), bf16, in-place into q ----------------
__global__ __launch_bounds__(256) void attn_spatial_kernel(
    ushort* __restrict__ q, const ushort* __restrict__ k, const ushort* __restrict__ v,
    const ushort* __restrict__ bias)
{
    const int nq = blockIdx.x, bt = blockIdx.y, h = blockIdx.z;
    __shared__ float qsh[64];
    __shared__ float s[NTOK];
    __shared__ float part[4][64];
    __shared__ float redm[4], reds[4];
    const int tid = threadIdx.x;
    if (tid < 64) qsh[tid] = bf2f(q[((size_t)nq * 64 + bt) * EMBED + h * 64 + tid]);
    __syncthreads();
    float lmax = -3.4e38f;
    for (int j = tid; j < NTOK; j += 256){
        const ushort* kr = &k[((size_t)j * 64 + bt) * EMBED + h * 64];
        const uint2* kr2 = (const uint2*)kr;
        float acc = 0.f;
        #pragma unroll
        for (int e4 = 0; e4 < 16; ++e4){
            uint2 u = kr2[e4];
            acc = fmaf(qsh[e4*4+0], bf2f((ushort)(u.x & 0xffff)), acc);
            acc = fmaf(qsh[e4*4+1], bf2f((ushort)(u.x >> 16)),    acc);
            acc = fmaf(qsh[e4*4+2], bf2f((ushort)(u.y & 0xffff)), acc);
            acc = fmaf(qsh[e4*4+3], bf2f((ushort)(u.y >> 16)),    acc);
        }
        acc += bf2f(bias[(size_t)h * (NTOK * NTOK) + (size_t)nq * NTOK + j]);
        s[j] = acc;
        lmax = fmaxf(lmax, acc);
    }
    #pragma unroll
    for (int off = 32; off >= 1; off >>= 1) lmax = fmaxf(lmax, __shfl_down(lmax, off));
    const int wid = tid >> 6;
    if ((tid & 63) == 0) redm[wid] = lmax;
    __syncthreads();
    lmax = fmaxf(fmaxf(redm[0], redm[1]), fmaxf(redm[2], redm[3]));
    float lsum = 0.f;
    for (int j = tid; j < NTOK; j += 256){
        float e = expf(s[j] - lmax);
        s[j] = e;
        lsum += e;
    }
    #pragma unroll
    for (int off = 32; off >= 1; off >>= 1) lsum += __shfl_down(lsum, off);
    if ((tid & 63) == 0) reds[wid] = lsum;
    __syncthreads();
    const float inv = 1.f / (reds[0] + reds[1] + reds[2] + reds[3]);
    const int d = tid & 63, g = tid >> 6;
    float o = 0.f;
    for (int j = g; j < NTOK; j += 4)
        o = fmaf(s[j], bf2f(v[((size_t)j * 64 + bt) * EMBED + h * 64 + d]), o);
    part[g][d] = o;
    __syncthreads();
    if (tid < 64)
        q[((size_t)nq * 64 + bt) * EMBED + h * 64 + tid] =
            f2bf((part[0][tid] + part[1][tid] + part[2][tid] + part[3][tid]) * inv);
}

// ---------------- relative-position bias gather (bf16) ----------------
__global__ void bias_gather_kernel(const float* __restrict__ rpw, const int* __restrict__ bucket,
                                   ushort* __restrict__ bias){
    const int i = blockIdx.x * 256 + threadIdx.x;
    const int total = HEADS * NTOK * NTOK;
    if (i < total){
        const int h = i / (NTOK * NTOK);
        const int ij = i % (NTOK * NTOK);
        bias[i] = f2bf(rpw[(size_t)bucket[ij] * HEADS + h]);
    }
}

// ---------------- host-side helpers ----------------
static inline void g(const ushort* A, const ushort* Bt, int M, int N, int K,
                     const float* bias, float scale, int dogelu,
                     const ushort* addb, const float* addf, const float* gvec,
                     void* C, int obf16, hipStream_t stream){
    dim3 grid(N / 128, (M + 127) / 128);
    mfma_gemm<<<grid, 256, 0, stream>>>(A, Bt, M, N, K, bias, scale, dogelu, addb, addf, gvec, C, obf16);
}
static inline void tr(const float* w, ushort* wt, int K, int N, hipStream_t stream){
    transpose_w<<<dim3(N / 32, K / 32), 256, 0, stream>>>(w, wt, K, N);
}

extern "C" void kernel_launch(void* const* d_in, const int* in_sizes, int n_in,
                              void* d_out, int out_size, void* d_ws, size_t ws_size,
                              hipStream_t stream){
    const float* x        = (const float*)d_in[0];
    const float* q_w      = (const float*)d_in[1];
    const float* k_w      = (const float*)d_in[2];
    const float* v_w      = (const float*)d_in[3];
    const float* out_w    = (const float*)d_in[4];
    const float* q_b      = (const float*)d_in[5];
    const float* v_b      = (const float*)d_in[6];
    const float* out_b    = (const float*)d_in[7];
    const float* attn_ln_w= (const float*)d_in[8];
    const float* attn_ln_b= (const float*)d_in[9];
    const float* sa_ln_w  = (const float*)d_in[10];
    const float* sa_ln_b  = (const float*)d_in[11];
    const float* fin_ln_w = (const float*)d_in[12];
    const float* fin_ln_b = (const float*)d_in[13];
    const float* wi0      = (const float*)d_in[14];
    const float* wi1      = (const float*)d_in[15];
    const float* ffn_ln_w = (const float*)d_in[16];
    const float* ffn_ln_b = (const float*)d_in[17];
    const float* ffn_out_w= (const float*)d_in[18];
    const float* ffn_out_b= (const float*)d_in[19];
    const float* gamma1   = (const float*)d_in[20];
    const float* gamma2   = (const float*)d_in[21];
    const float* t_fc1_w  = (const float*)d_in[22];
    const float* t_fc1_b  = (const float*)d_in[23];
    const float* t_fc2_w  = (const float*)d_in[24];
    const float* t_fc2_b  = (const float*)d_in[25];
    const float* s_fc1_w  = (const float*)d_in[26];
    const float* s_fc1_b  = (const float*)d_in[27];
    const float* s_fc2_w  = (const float*)d_in[28];
    const float* s_fc2_b  = (const float*)d_in[29];
    const float* m_fc1_w  = (const float*)d_in[30];
    const float* m_fc1_b  = (const float*)d_in[31];
    const float* m_fc2_w  = (const float*)d_in[32];
    const float* m_fc2_b  = (const float*)d_in[33];
    const float* rel_pos_w= (const float*)d_in[34];
    const int*   rp_bucket= (const int*)d_in[35];

    const size_t TOKD  = (size_t)TOK * EMBED;          // 25,264,128
    const size_t BIASZ = (size_t)HEADS * NTOK * NTOK;  //  1,585,176

    ushort* ws = (ushort*)d_ws;
    size_t off = 0;
    auto carve = [&](size_t n){ ushort* p = ws + off; off += n; return p; };

    // bf16-transposed weights
    ushort* WTQ  = carve((size_t)EMBED * EMBED);
    ushort* WTK  = carve((size_t)EMBED * EMBED);
    ushort* WTV  = carve((size_t)EMBED * EMBED);
    ushort* WTO  = carve((size_t)EMBED * EMBED);
    ushort* WTI0 = carve((size_t)FFN * EMBED);
    ushort* WTI1 = carve((size_t)FFN * EMBED);
    ushort* WTFO = carve((size_t)EMBED * FFN);
    ushort* WTT1 = carve((size_t)DA * EMBED);
    ushort* WTT2 = carve((size_t)EMBED * DA);
    ushort* WTS1 = carve((size_t)DA * EMBED);
    ushort* WTS2 = carve((size_t)EMBED * DA);
    ushort* WTM1 = carve((size_t)DA * EMBED);
    ushort* WTM2 = carve((size_t)EMBED * DA);
    // token-sized bf16 buffers
    ushort* WB0  = carve(TOKD);
    ushort* WB1  = carve(TOKD);
    ushort* BIAS = carve(BIASZ);
    // chunk scratch (union of attn-path and ffn-path layouts)
    const size_t s_attn = (size_t)CHA*EMBED + (size_t)CHA*EMBED + (size_t)CHA*DA;
    const size_t s_ffn  = (size_t)CHF*EMBED + 2*(size_t)CHF*FFN + (size_t)CHF*DA + 2*(size_t)CHF*EMBED;
    ushort* S = carve(s_attn > s_ffn ? s_attn : s_ffn);

    // attn-path views
    ushort* Lc  = S;
    ushort* AOc = S + (size_t)CHA * EMBED;
    ushort* ABa = AOc + (size_t)CHA * EMBED;
    // ffn-path views
    ushort* xnc = S;
    ushort* H0  = xnc + (size_t)CHF * EMBED;
    ushort* H1  = H0 + (size_t)CHF * FFN;
    ushort* ABf = H1 + (size_t)CHF * FFN;
    float*  MF  = (float*)(ABf + (size_t)CHF * DA);    // CHF x EMBED fp32

    const size_t need = off * sizeof(ushort);
    if (ws_size < need) return;   // diagnostic: zero output => ws too small

    // d_out hosts: V/K bf16 buffer (low half) + x2 bf16 (high half); final fp32 overwrites all
    ushort* WB2 = (ushort*)d_out;
    ushort* X2  = (ushort*)d_out + TOKD;
    float*  out = (float*)d_out;

    // ---------------- weight prep ----------------
    tr(q_w,   WTQ,  EMBED, EMBED, stream);
    tr(k_w,   WTK,  EMBED, EMBED, stream);
    tr(v_w,   WTV,  EMBED, EMBED, stream);
    tr(out_w, WTO,  EMBED, EMBED, stream);
    tr(wi0,   WTI0, EMBED, FFN,   stream);
    tr(wi1,   WTI1, EMBED, FFN,   stream);
    tr(ffn_out_w, WTFO, FFN, EMBED, stream);
    tr(t_fc1_w, WTT1, EMBED, DA, stream);
    tr(t_fc2_w, WTT2, DA, EMBED, stream);
    tr(s_fc1_w, WTS1, EMBED, DA, stream);
    tr(s_fc2_w, WTS2, DA, EMBED, stream);
    tr(m_fc1_w, WTM1, EMBED, DA, stream);
    tr(m_fc2_w, WTM2, DA, EMBED, stream);

    const float qs = 0.125f;  // HD^-0.5

    // ================= temporal attention =================
    for (int m0 = 0; m0 < TOK; m0 += CHA){
        const int mc = (TOK - m0 < CHA) ? (TOK - m0) : CHA;
        ln_kernel<float><<<mc, 256, 0, stream>>>(x + (size_t)m0*EMBED, Lc, sa_ln_w, sa_ln_b, EMBED);
        g(Lc, WTQ, mc, EMBED, EMBED, q_b, qs, 0, nullptr, nullptr, nullptr, WB0 + (size_t)m0*EMBED, 1, stream);
        g(Lc, WTK, mc, EMBED, EMBED, nullptr, 1.f, 0, nullptr, nullptr, nullptr, WB1 + (size_t)m0*EMBED, 1, stream);
        g(Lc, WTV, mc, EMBED, EMBED, v_b, 1.f, 0, nullptr, nullptr, nullptr, WB2 + (size_t)m0*EMBED, 1, stream);
    }
    attn_temporal_kernel<<<dim3(HEADS, NTOK, BV), 64, 0, stream>>>(WB0, WB1, WB2);
    for (int m0 = 0; m0 < TOK; m0 += CHA){
        const int mc = (TOK - m0 < CHA) ? (TOK - m0) : CHA;
        ln_kernel<ushort><<<mc, 256, 0, stream>>>(WB0 + (size_t)m0*EMBED, Lc, attn_ln_w, attn_ln_b, EMBED);
        g(Lc, WTO, mc, EMBED, EMBED, out_b, 1.f, 0, nullptr, nullptr, nullptr, AOc, 1, stream);
        g(AOc, WTT1, mc, DA, EMBED, t_fc1_b, 1.f, 1, nullptr, nullptr, nullptr, ABa, 1, stream);
        // x1 = x + adapter_t  -> WB1 (K dead)
        g(ABa, WTT2, mc, EMBED, DA, t_fc2_b, 1.f, 0, nullptr, x + (size_t)m0*EMBED, nullptr,
          WB1 + (size_t)m0*EMBED, 1, stream);
    }

    // ================= spatial attention =================
    for (int m0 = 0; m0 < TOK; m0 += CHA){
        const int mc = (TOK - m0 < CHA) ? (TOK - m0) : CHA;
        ln_kernel<ushort><<<mc, 256, 0, stream>>>(WB1 + (size_t)m0*EMBED, Lc, sa_ln_w, sa_ln_b, EMBED);
        g(Lc, WTQ, mc, EMBED, EMBED, q_b, qs, 0, nullptr, nullptr, nullptr, WB0 + (size_t)m0*EMBED, 1, stream);
        g(Lc, WTK, mc, EMBED, EMBED, nullptr, 1.f, 0, nullptr, nullptr, nullptr, WB2 + (size_t)m0*EMBED, 1, stream);
        g(Lc, WTV, mc, EMBED, EMBED, v_b, 1.f, 0, nullptr, nullptr, nullptr, WB1 + (size_t)m0*EMBED, 1, stream);
    }
    {
        const int total = HEADS * NTOK * NTOK;
        bias_gather_kernel<<<(total + 255) / 256, 256, 0, stream>>>(rel_pos_w, rp_bucket, BIAS);
    }
    attn_spatial_kernel<<<dim3(NTOK, BT, HEADS), 256, 0, stream>>>(WB0, WB2, WB1, BIAS);
    for (int m0 = 0; m0 < TOK; m0 += CHA){
        const int mc = (TOK - m0 < CHA) ? (TOK - m0) : CHA;
        ln_kernel<ushort><<<mc, 256, 0, stream>>>(WB0 + (size_t)m0*EMBED, Lc, attn_ln_w, attn_ln_b, EMBED);
        g(Lc, WTO, mc, EMBED, EMBED, out_b, 1.f, 0, nullptr, nullptr, nullptr, AOc, 1, stream);  // aos
        g(AOc, WTS1, mc, DA, EMBED, s_fc1_b, 1.f, 1, nullptr, nullptr, nullptr, ABa, 1, stream);
        // x2 = x + gamma1*(aos + adapter) -> X2 bf16
        g(ABa, WTS2, mc, EMBED, DA, s_fc2_b, 1.f, 0, AOc, x + (size_t)m0*EMBED, gamma1,
          X2 + (size_t)m0*EMBED, 1, stream);
    }

    // ================= FFN (GEGLU + inner LN) + adapter m + final combine =================
    for (int m0 = 0; m0 < TOK; m0 += CHF){
        const int mc = (TOK - m0 < CHF) ? (TOK - m0) : CHF;
        ln_kernel<ushort><<<mc, 256, 0, stream>>>(X2 + (size_t)m0*EMBED, xnc, fin_ln_w, fin_ln_b, EMBED);
        g(xnc, WTI0, mc, FFN, EMBED, nullptr, 1.f, 1, nullptr, nullptr, nullptr, H0, 1, stream);  // gelu(xn@wi0)
        g(xnc, WTI1, mc, FFN, EMBED, nullptr, 1.f, 0, nullptr, nullptr, nullptr, H1, 1, stream);
        lnmul_kernel<<<mc, 256, 0, stream>>>(H0, H1, H0, ffn_ln_w, ffn_ln_b, FFN);               // in-place
        g(xnc, WTM1, mc, DA, EMBED, m_fc1_b, 1.f, 1, nullptr, nullptr, nullptr, ABf, 1, stream);
        g(ABf, WTM2, mc, EMBED, DA, m_fc2_b, 1.f, 0, X2 + (size_t)m0*EMBED, nullptr, nullptr, MF, 0, stream); // x2+madapt
        g(H0, WTFO, mc, EMBED, FFN, ffn_out_b, 1.f, 0, nullptr, MF, gamma2, out + (size_t)m0*EMBED, 0, stream);
    }
}

// Round 4
// 12904.689 us; speedup vs baseline: 3.5105x; 1.7043x over previous
//
#include <hip/hip_runtime.h>
#include <hip/hip_bf16.h>
#include <math.h>

// ---------------- constants ----------------
#define EMBED 1536
#define HEADS 24
#define HD 64
#define FFN 6144
#define NTOK 257          // sequence length (spatial)
#define BT 64             // b*t
#define TT 8              // frames
#define BV 8              // videos
#define TOK (NTOK*BT)     // 16448 token rows
#define DA 384            // adapter hidden
#define NRD 964
#define CHF 1536          // FFN-path row chunk

typedef __bf16 bf16x8_t __attribute__((ext_vector_type(8)));
typedef float  f32x4    __attribute__((ext_vector_type(4)));

__device__ __forceinline__ float gelu_f(float x){
    return 0.5f * x * (1.0f + erff(x * 0.7071067811865476f));
}
__device__ __forceinline__ float bf2f(ushort u){
    union { uint i; float f; } c; c.i = ((uint)u) << 16; return c.f;
}
__device__ __forceinline__ ushort f2bf(float f){
    union { float f; uint i; } c; c.f = f;
    uint r = (c.i + 0x7fffu + ((c.i >> 16) & 1u)) >> 16;
    return (ushort)r;
}

// ---------------- weight transpose + bf16 convert + scale: w[K][N] -> wt[N][K] ----------------
__global__ __launch_bounds__(256) void transpose_w(const float* __restrict__ w, ushort* __restrict__ wt,
                                                   int K, int N, float scale){
    __shared__ float t[32][33];
    const int n0 = blockIdx.x * 32, k0 = blockIdx.y * 32;
    const int tx = threadIdx.x & 31, ty = threadIdx.x >> 5;   // 32 x 8
    #pragma unroll
    for (int i = 0; i < 4; ++i)
        t[ty + 8*i][tx] = w[(size_t)(k0 + ty + 8*i) * N + n0 + tx];
    __syncthreads();
    #pragma unroll
    for (int i = 0; i < 4; ++i)
        wt[(size_t)(n0 + ty + 8*i) * K + k0 + tx] = f2bf(t[tx][ty + 8*i] * scale);
}

// ---------------- combined QKV bias: [q_b*0.125 | 0 | v_b] ----------------
__global__ void build_qkv_bias(const float* __restrict__ qb, const float* __restrict__ vb,
                               float* __restrict__ o){
    int c = blockIdx.x * 256 + threadIdx.x;
    if (c < 1536) o[c] = qb[c] * 0.125f;
    else if (c < 3072) o[c] = 0.f;
    else if (c < 4608) o[c] = vb[c - 3072];
}

// ---------------- LayerNorm (templated input dtype), bf16 output ----------------
template<typename TI>
__global__ __launch_bounds__(256) void ln_kernel(const TI* __restrict__ in, ushort* __restrict__ out,
                                                 const float* __restrict__ w, const float* __restrict__ b, int D){
    __shared__ float shs[4], shss[4];
    const int row = blockIdx.x;
    const TI* xr = in + (size_t)row * D;
    float s = 0.f, ss = 0.f;
    for (int i = threadIdx.x * 8; i < D; i += 2048){
        float vv[8];
        if constexpr (sizeof(TI) == 4){
            float4 a = *(const float4*)&xr[i];
            float4 c = *(const float4*)&xr[i + 4];
            vv[0]=a.x; vv[1]=a.y; vv[2]=a.z; vv[3]=a.w;
            vv[4]=c.x; vv[5]=c.y; vv[6]=c.z; vv[7]=c.w;
        } else {
            int4 u = *(const int4*)&xr[i];
            const ushort* up = (const ushort*)&u;
            #pragma unroll
            for (int j = 0; j < 8; ++j) vv[j] = bf2f(up[j]);
        }
        #pragma unroll
        for (int j = 0; j < 8; ++j){ s += vv[j]; ss += vv[j]*vv[j]; }
    }
    #pragma unroll
    for (int off = 32; off >= 1; off >>= 1){ s += __shfl_down(s, off); ss += __shfl_down(ss, off); }
    const int wid = threadIdx.x >> 6;
    if ((threadIdx.x & 63) == 0){ shs[wid] = s; shss[wid] = ss; }
    __syncthreads();
    s  = shs[0] + shs[1] + shs[2] + shs[3];
    ss = shss[0] + shss[1] + shss[2] + shss[3];
    const float mu  = s / D;
    const float inv = rsqrtf(ss / D - mu * mu + 1e-5f);
    ushort* orow = out + (size_t)row * D;
    for (int i = threadIdx.x * 8; i < D; i += 2048){
        float vv[8];
        if constexpr (sizeof(TI) == 4){
            float4 a = *(const float4*)&xr[i];
            float4 c = *(const float4*)&xr[i + 4];
            vv[0]=a.x; vv[1]=a.y; vv[2]=a.z; vv[3]=a.w;
            vv[4]=c.x; vv[5]=c.y; vv[6]=c.z; vv[7]=c.w;
        } else {
            int4 u = *(const int4*)&xr[i];
            const ushort* up = (const ushort*)&u;
            #pragma unroll
            for (int j = 0; j < 8; ++j) vv[j] = bf2f(up[j]);
        }
        ushort ov[8];
        #pragma unroll
        for (int j = 0; j < 8; ++j)
            ov[j] = f2bf((vv[j] - mu) * inv * w[i + j] + b[i + j]);
        *(int4*)&orow[i] = *(const int4*)ov;
    }
}

// ---------------- fused gate (a*b) + LayerNorm, bf16 in/out ----------------
__global__ __launch_bounds__(256) void lnmul_kernel(const ushort* __restrict__ ina, const ushort* __restrict__ inb,
                                                    ushort* __restrict__ out,
                                                    const float* __restrict__ w, const float* __restrict__ b, int D){
    __shared__ float shs[4], shss[4];
    const int row = blockIdx.x;
    const ushort* ar = ina + (size_t)row * D;
    const ushort* br = inb + (size_t)row * D;
    float s = 0.f, ss = 0.f;
    for (int i = threadIdx.x * 8; i < D; i += 2048){
        int4 ua = *(const int4*)&ar[i];
        int4 ub = *(const int4*)&br[i];
        const ushort* pa = (const ushort*)&ua;
        const ushort* pb = (const ushort*)&ub;
        #pragma unroll
        for (int j = 0; j < 8; ++j){ float v = bf2f(pa[j]) * bf2f(pb[j]); s += v; ss += v*v; }
    }
    #pragma unroll
    for (int off = 32; off >= 1; off >>= 1){ s += __shfl_down(s, off); ss += __shfl_down(ss, off); }
    const int wid = threadIdx.x >> 6;
    if ((threadIdx.x & 63) == 0){ shs[wid] = s; shss[wid] = ss; }
    __syncthreads();
    s  = shs[0] + shs[1] + shs[2] + shs[3];
    ss = shss[0] + shss[1] + shss[2] + shss[3];
    const float mu  = s / D;
    const float inv = rsqrtf(ss / D - mu * mu + 1e-5f);
    ushort* orow = out + (size_t)row * D;
    for (int i = threadIdx.x * 8; i < D; i += 2048){
        int4 ua = *(const int4*)&ar[i];
        int4 ub = *(const int4*)&br[i];
        const ushort* pa = (const ushort*)&ua;
        const ushort* pb = (const ushort*)&ub;
        ushort ov[8];
        #pragma unroll
        for (int j = 0; j < 8; ++j){
            float v = bf2f(pa[j]) * bf2f(pb[j]);
            ov[j] = f2bf((v - mu) * inv * w[i + j] + b[i + j]);
        }
        *(int4*)&orow[i] = *(const int4*)ov;
    }
}

// ---------------- bf16 MFMA GEMM with register-prefetch pipeline ----------------
// A[M][K] x Bt[N][K]^T -> C[M][N]
// epilogue: v=acc; (+bias[c_glob]); gelu?; (+bf16 addb); (*gvec[c_loc]); (+bf16 addb2); (+f32 addf)
// mode 0: single output C0. mode 1: QKV 3-way split at col 1536 (C0,C1,C2 each N_out=1536).
// mode 2: FFN pair split at col 6144 (C0 gelu'd, C1 plain; each N_out=6144).
__global__ __launch_bounds__(256) void mfma_gemm(
    const ushort* __restrict__ A, const ushort* __restrict__ Bt,
    int M, int N, int K,
    const float* __restrict__ bias, int dogelu,
    const ushort* __restrict__ addb, const float* __restrict__ gvec,
    const ushort* __restrict__ addb2, const float* __restrict__ addf,
    void* __restrict__ C0, void* __restrict__ C1, void* __restrict__ C2,
    int mode, int obf16)
{
    __shared__ ushort As[4096];   // 128 rows x 32 k, fragment-subtile order
    __shared__ ushort Bs[4096];
    const int tid  = threadIdx.x;
    const int lane = tid & 63, wv = tid >> 6;
    const int wr = wv >> 1, wc = wv & 1;
    const int row0 = blockIdx.y * 128, col0 = blockIdx.x * 128;

    const int crow = tid >> 2;          // 0..63
    const int ckb  = tid & 3;           // k-block of 8
    int ra0 = row0 + crow;       if (ra0 >= M) ra0 = M - 1;
    int ra1 = row0 + crow + 64;  if (ra1 >= M) ra1 = M - 1;
    const ushort* Ap0 = A  + (size_t)ra0 * K + ckb * 8;
    const ushort* Ap1 = A  + (size_t)ra1 * K + ckb * 8;
    const ushort* Bp0 = Bt + (size_t)(col0 + crow) * K + ckb * 8;
    const ushort* Bp1 = Bt + (size_t)(col0 + crow + 64) * K + ckb * 8;
    const int d0 = ((crow >> 4) << 9) + ((ckb << 4) + (crow & 15)) * 8;
    const int d1 = (((crow + 64) >> 4) << 9) + ((ckb << 4) + (crow & 15)) * 8;

    f32x4 acc[4][4] = {};
    const int nK = K >> 5;

    // prefetch step 0
    int4 a0 = *(const int4*)Ap0, a1 = *(const int4*)Ap1;
    int4 b0 = *(const int4*)Bp0, b1 = *(const int4*)Bp1;

    for (int ks = 0; ks < nK; ++ks){
        __syncthreads();
        *(int4*)&As[d0] = a0; *(int4*)&As[d1] = a1;
        *(int4*)&Bs[d0] = b0; *(int4*)&Bs[d1] = b1;
        __syncthreads();
        if (ks + 1 < nK){                 // issue next-step loads; latency hides under MFMA
            const int ko = (ks + 1) << 5;
            a0 = *(const int4*)(Ap0 + ko); a1 = *(const int4*)(Ap1 + ko);
            b0 = *(const int4*)(Bp0 + ko); b1 = *(const int4*)(Bp1 + ko);
        }
        bf16x8_t af[4], bfr[4];
        #pragma unroll
        for (int mi = 0; mi < 4; ++mi)
            af[mi] = *(const bf16x8_t*)&As[(((wr<<2)+mi) << 9) + lane * 8];
        #pragma unroll
        for (int ni = 0; ni < 4; ++ni)
            bfr[ni] = *(const bf16x8_t*)&Bs[(((wc<<2)+ni) << 9) + lane * 8];
        #pragma unroll
        for (int mi = 0; mi < 4; ++mi)
            #pragma unroll
            for (int ni = 0; ni < 4; ++ni)
                acc[mi][ni] = __builtin_amdgcn_mfma_f32_16x16x32_bf16(af[mi], bfr[ni], acc[mi][ni], 0, 0, 0);
    }

    // ---- output routing (block-uniform: 1536 and 6144 are multiples of 128) ----
    int cb = col0, Nout = N, gel = dogelu;
    void* Cp = C0;
    if (mode == 1){
        int seg = col0 / 1536;
        Cp = (seg == 0) ? C0 : ((seg == 1) ? C1 : C2);
        cb = col0 - seg * 1536; Nout = 1536;
    } else if (mode == 2){
        int seg = col0 / 6144;
        Cp = seg ? C1 : C0;
        cb = col0 - seg * 6144; Nout = 6144;
        if (seg) gel = 0;
    }

    const int fr = lane >> 4;   // 0..3
    const int fc = lane & 15;
    #pragma unroll
    for (int mi = 0; mi < 4; ++mi){
        #pragma unroll
        for (int j = 0; j < 4; ++j){
            const int r = row0 + wr*64 + mi*16 + fr*4 + j;
            if (r < M){
                #pragma unroll
                for (int ni = 0; ni < 4; ++ni){
                    const int cg = col0 + wc*64 + ni*16 + fc;          // global col (bias)
                    const int cl = cb   + wc*64 + ni*16 + fc;          // local col
                    float v = acc[mi][ni][j];
                    if (bias) v += bias[cg];
                    if (gel)  v = gelu_f(v);
                    if (addb)  v += bf2f(addb [(size_t)r*Nout + cl]);
                    if (gvec)  v *= gvec[cl];
                    if (addb2) v += bf2f(addb2[(size_t)r*Nout + cl]);
                    if (addf)  v += addf[(size_t)r*Nout + cl];
                    if (obf16) ((ushort*)Cp)[(size_t)r*Nout + cl] = f2bf(v);
                    else       ((float*) Cp)[(size_t)r*Nout + cl] = v;
                }
            }
        }
    }
}

// ---------------- temporal attention: L=8 over frames, bf16, in-place into q ----------------
__global__ __launch_bounds__(64) void attn_temporal_kernel(
    ushort* __restrict__ q, const ushort* __restrict__ k, const ushort* __restrict__ v)
{
    const int h = blockIdx.x, n = blockIdx.y, b = blockIdx.z;
    const int d = threadIdx.x;
    __shared__ float qs[8][64], ks[8][64], vs[8][64];
    __shared__ float sc[8][8], pr[8][8];
    #pragma unroll
    for (int t = 0; t < 8; ++t){
        size_t r = ((size_t)n * 64 + b * 8 + t) * EMBED + h * 64 + d;
        qs[t][d] = bf2f(q[r]); ks[t][d] = bf2f(k[r]); vs[t][d] = bf2f(v[r]);
    }
    __syncthreads();
    {
        const int qi = d >> 3, kj = d & 7;
        float s = 0.f;
        #pragma unroll
        for (int e = 0; e < 64; ++e) s = fmaf(qs[qi][e], ks[kj][e], s);
        sc[qi][kj] = s;
    }
    __syncthreads();
    if (d < 8){
        float m = -3.4e38f;
        #pragma unroll
        for (int j = 0; j < 8; ++j) m = fmaxf(m, sc[d][j]);
        float sum = 0.f;
        #pragma unroll
        for (int j = 0; j < 8; ++j){ float e = expf(sc[d][j] - m); pr[d][j] = e; sum += e; }
        const float inv = 1.f / sum;
        #pragma unroll
        for (int j = 0; j < 8; ++j) pr[d][j] *= inv;
    }
    __syncthreads();
    #pragma unroll
    for (int qi = 0; qi < 8; ++qi){
        float o = 0.f;
        #pragma unroll
        for (int t = 0; t < 8; ++t) o = fmaf(pr[qi][t], vs[t][d], o);
        q[((size_t)n * 64 + b * 8 + qi) * EMBED + h * 64 + d] = f2bf(o);
    }
}

// ---------------- spatial attention: one block per (query n, bt, head), bf16, in-place into q ----------------
__global__ __launch_bounds__(256) void attn_spatial_kernel(
    ushort* __restrict__ q, const ushort* __restrict__ k, const ushort* __restrict__ v,
    const ushort* __restrict__ bias)
{
    const int nq = blockIdx.x, bt = blockIdx.y, h = blockIdx.z;
    __shared__ float qsh[64];
    __shared__ float s[NTOK];
    __shared__ float part[4][64];
    __shared__ float redm[4], reds[4];
    const int tid = threadIdx.x;
    if (tid < 64) qsh[tid] = bf2f(q[((size_t)nq * 64 + bt) * EMBED + h * 64 + tid]);
    __syncthreads();
    float lmax = -3.4e38f;
    for (int j = tid; j < NTOK; j += 256){
        const ushort* kr = &k[((size_t)j * 64 + bt) * EMBED + h * 64];
        const uint2* kr2 = (const uint2*)kr;
        float acc = 0.f;
        #pragma unroll
        for (int e4 = 0; e4 < 16; ++e4){
            uint2 u = kr2[e4];
            acc = fmaf(qsh[e4*4+0], bf2f((ushort)(u.x & 0xffff)), acc);
            acc = fmaf(qsh[e4*4+1], bf2f((ushort)(u.x >> 16)),    acc);
            acc = fmaf(qsh[e4*4+2], bf2f((ushort)(u.y & 0xffff)), acc);
            acc = fmaf(qsh[e4*4+3], bf2f((ushort)(u.y >> 16)),    acc);
        }
        acc += bf2f(bias[(size_t)h * (NTOK * NTOK) + (size_t)nq * NTOK + j]);
        s[j] = acc;
        lmax = fmaxf(lmax, acc);
    }
    #pragma unroll
    for (int off = 32; off >= 1; off >>= 1) lmax = fmaxf(lmax, __shfl_down(lmax, off));
    const int wid = tid >> 6;
    if ((tid & 63) == 0) redm[wid] = lmax;
    __syncthreads();
    lmax = fmaxf(fmaxf(redm[0], redm[1]), fmaxf(redm[2], redm[3]));
    float lsum = 0.f;
    for (int j = tid; j < NTOK; j += 256){
        float e = expf(s[j] - lmax);
        s[j] = e;
        lsum += e;
    }
    #pragma unroll
    for (int off = 32; off >= 1; off >>= 1) lsum += __shfl_down(lsum, off);
    if ((tid & 63) == 0) reds[wid] = lsum;
    __syncthreads();
    const float inv = 1.f / (reds[0] + reds[1] + reds[2] + reds[3]);
    const int d = tid & 63, g = tid >> 6;
    float o = 0.f;
    for (int j = g; j < NTOK; j += 4)
        o = fmaf(s[j], bf2f(v[((size_t)j * 64 + bt) * EMBED + h * 64 + d]), o);
    part[g][d] = o;
    __syncthreads();
    if (tid < 64)
        q[((size_t)nq * 64 + bt) * EMBED + h * 64 + tid] =
            f2bf((part[0][tid] + part[1][tid] + part[2][tid] + part[3][tid]) * inv);
}

// ---------------- relative-position bias gather (bf16) ----------------
__global__ void bias_gather_kernel(const float* __restrict__ rpw, const int* __restrict__ bucket,
                                   ushort* __restrict__ bias){
    const int i = blockIdx.x * 256 + threadIdx.x;
    const int total = HEADS * NTOK * NTOK;
    if (i < total){
        const int h = i / (NTOK * NTOK);
        const int ij = i % (NTOK * NTOK);
        bias[i] = f2bf(rpw[(size_t)bucket[ij] * HEADS + h]);
    }
}

// ---------------- host-side helpers ----------------
static inline void g(const ushort* A, const ushort* Bt, int M, int N, int K,
                     const float* bias, int dogelu,
                     const ushort* addb, const float* gvec,
                     const ushort* addb2, const float* addf,
                     void* C0, void* C1, void* C2, int mode, int obf16, hipStream_t stream){
    dim3 grid(N / 128, (M + 127) / 128);
    mfma_gemm<<<grid, 256, 0, stream>>>(A, Bt, M, N, K, bias, dogelu, addb, gvec, addb2, addf,
                                        C0, C1, C2, mode, obf16);
}
static inline void tr(const float* w, ushort* wt, int K, int N, float sc, hipStream_t stream){
    transpose_w<<<dim3(N / 32, K / 32), 256, 0, stream>>>(w, wt, K, N, sc);
}

extern "C" void kernel_launch(void* const* d_in, const int* in_sizes, int n_in,
                              void* d_out, int out_size, void* d_ws, size_t ws_size,
                              hipStream_t stream){
    const float* x        = (const float*)d_in[0];
    const float* q_w      = (const float*)d_in[1];
    const float* k_w      = (const float*)d_in[2];
    const float* v_w      = (const float*)d_in[3];
    const float* out_w    = (const float*)d_in[4];
    const float* q_b      = (const float*)d_in[5];
    const float* v_b      = (const float*)d_in[6];
    const float* out_b    = (const float*)d_in[7];
    const float* attn_ln_w= (const float*)d_in[8];
    const float* attn_ln_b= (const float*)d_in[9];
    const float* sa_ln_w  = (const float*)d_in[10];
    const float* sa_ln_b  = (const float*)d_in[11];
    const float* fin_ln_w = (const float*)d_in[12];
    const float* fin_ln_b = (const float*)d_in[13];
    const float* wi0      = (const float*)d_in[14];
    const float* wi1      = (const float*)d_in[15];
    const float* ffn_ln_w = (const float*)d_in[16];
    const float* ffn_ln_b = (const float*)d_in[17];
    const float* ffn_out_w= (const float*)d_in[18];
    const float* ffn_out_b= (const float*)d_in[19];
    const float* gamma1   = (const float*)d_in[20];
    const float* gamma2   = (const float*)d_in[21];
    const float* t_fc1_w  = (const float*)d_in[22];
    const float* t_fc1_b  = (const float*)d_in[23];
    const float* t_fc2_w  = (const float*)d_in[24];
    const float* t_fc2_b  = (const float*)d_in[25];
    const float* s_fc1_w  = (const float*)d_in[26];
    const float* s_fc1_b  = (const float*)d_in[27];
    const float* s_fc2_w  = (const float*)d_in[28];
    const float* s_fc2_b  = (const float*)d_in[29];
    const float* m_fc1_w  = (const float*)d_in[30];
    const float* m_fc1_b  = (const float*)d_in[31];
    const float* m_fc2_w  = (const float*)d_in[32];
    const float* m_fc2_b  = (const float*)d_in[33];
    const float* rel_pos_w= (const float*)d_in[34];
    const int*   rp_bucket= (const int*)d_in[35];

    const size_t TOKD  = (size_t)TOK * EMBED;          // 25,264,128
    const size_t BIASZ = (size_t)HEADS * NTOK * NTOK;  //  1,585,176

    ushort* ws = (ushort*)d_ws;
    size_t off = 0;
    auto carve = [&](size_t n){ ushort* p = ws + off; off += n; return p; };

    // bf16-transposed weights
    ushort* WQKV = carve((size_t)4608 * EMBED);        // [Q|K|V] rows, Q pre-scaled by 0.125
    ushort* WTO  = carve((size_t)EMBED * EMBED);
    ushort* WI01 = carve((size_t)2 * FFN * EMBED);     // [wi0 | wi1] rows
    ushort* WTFO = carve((size_t)EMBED * FFN);
    ushort* WTT1 = carve((size_t)DA * EMBED);
    ushort* WTT2 = carve((size_t)EMBED * DA);
    ushort* WTS1 = carve((size_t)DA * EMBED);
    ushort* WTS2 = carve((size_t)EMBED * DA);
    ushort* WTM1 = carve((size_t)DA * EMBED);
    ushort* WTM2 = carve((size_t)EMBED * DA);
    // token-sized bf16 buffers (2 in ws; 2 more live in d_out)
    ushort* WB0  = carve(TOKD);
    ushort* WB1  = carve(TOKD);
    ushort* BIAS = carve(BIASZ);
    float*  B4608= (float*)carve(9216);                // 4608 fp32
    // scratch union: adapter-hidden full (attn+ffn phases) vs H0|H1 (ffn chunk loop)
    const size_t s_ab = (size_t)TOK * DA;              //  6,316,032
    const size_t s_h  = (size_t)2 * CHF * FFN;         // 18,874,368
    ushort* SCR = carve(s_h > s_ab ? s_h : s_ab);
    ushort* AB  = SCR;                                 // TOK x DA
    ushort* H0  = SCR;                                 // CHF x FFN
    ushort* H1  = SCR + (size_t)CHF * FFN;

    const size_t need = off * sizeof(ushort);
    if (ws_size < need) return;   // diagnostic: zero output => ws too small

    // d_out hosts two bf16 token buffers; final fp32 result overwrites both
    ushort* WB2 = (ushort*)d_out;          // low half
    ushort* X2  = (ushort*)d_out + TOKD;   // high half (LN buf / x2)
    float*  out = (float*)d_out;

    // ---------------- weight prep ----------------
    tr(q_w,   WQKV,                   EMBED, EMBED, 0.125f, stream);
    tr(k_w,   WQKV + (size_t)1536*EMBED, EMBED, EMBED, 1.f, stream);
    tr(v_w,   WQKV + (size_t)3072*EMBED, EMBED, EMBED, 1.f, stream);
    tr(out_w, WTO,  EMBED, EMBED, 1.f, stream);
    tr(wi0,   WI01,                    EMBED, FFN, 1.f, stream);
    tr(wi1,   WI01 + (size_t)FFN*EMBED, EMBED, FFN, 1.f, stream);
    tr(ffn_out_w, WTFO, FFN, EMBED, 1.f, stream);
    tr(t_fc1_w, WTT1, EMBED, DA, 1.f, stream);
    tr(t_fc2_w, WTT2, DA, EMBED, 1.f, stream);
    tr(s_fc1_w, WTS1, EMBED, DA, 1.f, stream);
    tr(s_fc2_w, WTS2, DA, EMBED, 1.f, stream);
    tr(m_fc1_w, WTM1, EMBED, DA, 1.f, stream);
    tr(m_fc2_w, WTM2, DA, EMBED, 1.f, stream);
    build_qkv_bias<<<18, 256, 0, stream>>>(q_b, v_b, B4608);
    bias_gather_kernel<<<(HEADS*NTOK*NTOK + 255)/256, 256, 0, stream>>>(rel_pos_w, rp_bucket, BIAS);

    // ================= temporal attention =================
    ln_kernel<float><<<TOK, 256, 0, stream>>>(x, X2, sa_ln_w, sa_ln_b, EMBED);
    g(X2, WQKV, TOK, 4608, EMBED, B4608, 0, nullptr, nullptr, nullptr, nullptr,
      WB0, WB1, WB2, 1, 1, stream);                                   // Q->WB0 K->WB1 V->WB2
    attn_temporal_kernel<<<dim3(HEADS, NTOK, BV), 64, 0, stream>>>(WB0, WB1, WB2);
    ln_kernel<ushort><<<TOK, 256, 0, stream>>>(WB0, X2, attn_ln_w, attn_ln_b, EMBED);
    g(X2, WTO, TOK, EMBED, EMBED, out_b, 0, nullptr, nullptr, nullptr, nullptr,
      WB2, nullptr, nullptr, 0, 1, stream);                           // AO -> WB2 (V dead)
    g(WB2, WTT1, TOK, DA, EMBED, t_fc1_b, 1, nullptr, nullptr, nullptr, nullptr,
      AB, nullptr, nullptr, 0, 1, stream);
    g(AB, WTT2, TOK, EMBED, DA, t_fc2_b, 0, nullptr, nullptr, nullptr, x,
      WB1, nullptr, nullptr, 0, 1, stream);                           // x1 = x + adapt_t -> WB1

    // ================= spatial attention =================
    ln_kernel<ushort><<<TOK, 256, 0, stream>>>(WB1, X2, sa_ln_w, sa_ln_b, EMBED);
    g(X2, WQKV, TOK, 4608, EMBED, B4608, 0, nullptr, nullptr, nullptr, nullptr,
      WB0, WB2, WB1, 1, 1, stream);                                   // Q->WB0 K->WB2 V->WB1
    attn_spatial_kernel<<<dim3(NTOK, BT, HEADS), 256, 0, stream>>>(WB0, WB2, WB1, BIAS);
    ln_kernel<ushort><<<TOK, 256, 0, stream>>>(WB0, X2, attn_ln_w, attn_ln_b, EMBED);
    g(X2, WTO, TOK, EMBED, EMBED, out_b, 0, nullptr, nullptr, nullptr, nullptr,
      WB2, nullptr, nullptr, 0, 1, stream);                           // aos -> WB2
    g(WB2, WTS1, TOK, DA, EMBED, s_fc1_b, 1, nullptr, nullptr, nullptr, nullptr,
      AB, nullptr, nullptr, 0, 1, stream);
    // x2 = x + gamma1*(aos + acc + s_fc2_b)  -> X2 (bf16)
    g(AB, WTS2, TOK, EMBED, DA, s_fc2_b, 0, WB2, gamma1, nullptr, x,
      X2, nullptr, nullptr, 0, 1, stream);

    // ================= FFN (GEGLU + inner LN) + adapter m + final combine =================
    ln_kernel<ushort><<<TOK, 256, 0, stream>>>(X2, WB0, fin_ln_w, fin_ln_b, EMBED);   // xn -> WB0
    g(WB0, WTM1, TOK, DA, EMBED, m_fc1_b, 1, nullptr, nullptr, nullptr, nullptr,
      AB, nullptr, nullptr, 0, 1, stream);
    // Madd = x2 + adapter_m -> WB1 (bf16)
    g(AB, WTM2, TOK, EMBED, DA, m_fc2_b, 0, X2, nullptr, nullptr, nullptr,
      WB1, nullptr, nullptr, 0, 1, stream);
    for (int m0 = 0; m0 < TOK; m0 += CHF){
        const int mc = (TOK - m0 < CHF) ? (TOK - m0) : CHF;
        // H0 = gelu(xn@wi0), H1 = xn@wi1  (merged, N=12288)
        g(WB0 + (size_t)m0*EMBED, WI01, mc, 2*FFN, EMBED, nullptr, 2, nullptr, nullptr, nullptr, nullptr,
          H0, H1, nullptr, 2, 1, stream);
        lnmul_kernel<<<mc, 256, 0, stream>>>(H0, H1, H0, ffn_ln_w, ffn_ln_b, FFN);
        // out = gamma2*(acc + ffn_out_b) + Madd   (fp32 -> d_out)
        g(H0, WTFO, mc, EMBED, FFN, ffn_out_b, 0, nullptr, gamma2, WB1 + (size_t)m0*EMBED, nullptr,
          out + (size_t)m0*EMBED, nullptr, nullptr, 0, 0, stream);
    }
}

// Round 5
// 5962.156 us; speedup vs baseline: 7.5983x; 2.1644x over previous
//
#include <hip/hip_runtime.h>
#include <hip/hip_bf16.h>
#include <math.h>

// ---------------- constants ----------------
#define EMBED 1536
#define HEADS 24
#define HD 64
#define FFN 6144
#define NTOK 257          // sequence length (spatial)
#define BT 64             // b*t
#define TT 8              // frames
#define BV 8              // videos
#define TOK (NTOK*BT)     // 16448 token rows
#define DA 384            // adapter hidden
#define NRD 964
#define CHF 1536          // FFN-path row chunk

typedef __bf16 bf16x8_t __attribute__((ext_vector_type(8)));
typedef float  f32x4    __attribute__((ext_vector_type(4)));

__device__ __forceinline__ float gelu_f(float x){
    return 0.5f * x * (1.0f + erff(x * 0.7071067811865476f));
}
__device__ __forceinline__ float bf2f(ushort u){
    union { uint i; float f; } c; c.i = ((uint)u) << 16; return c.f;
}
__device__ __forceinline__ ushort f2bf(float f){
    union { float f; uint i; } c; c.f = f;
    uint r = (c.i + 0x7fffu + ((c.i >> 16) & 1u)) >> 16;
    return (ushort)r;
}

// ---------------- weight transpose + bf16 convert + scale: w[K][N] -> wt[N][K] ----------------
__global__ __launch_bounds__(256) void transpose_w(const float* __restrict__ w, ushort* __restrict__ wt,
                                                   int K, int N, float scale){
    __shared__ float t[32][33];
    const int n0 = blockIdx.x * 32, k0 = blockIdx.y * 32;
    const int tx = threadIdx.x & 31, ty = threadIdx.x >> 5;   // 32 x 8
    #pragma unroll
    for (int i = 0; i < 4; ++i)
        t[ty + 8*i][tx] = w[(size_t)(k0 + ty + 8*i) * N + n0 + tx];
    __syncthreads();
    #pragma unroll
    for (int i = 0; i < 4; ++i)
        wt[(size_t)(n0 + ty + 8*i) * K + k0 + tx] = f2bf(t[tx][ty + 8*i] * scale);
}

// ---------------- combined QKV bias: [q_b*0.125 | 0 | v_b] ----------------
__global__ void build_qkv_bias(const float* __restrict__ qb, const float* __restrict__ vb,
                               float* __restrict__ o){
    int c = blockIdx.x * 256 + threadIdx.x;
    if (c < 1536) o[c] = qb[c] * 0.125f;
    else if (c < 3072) o[c] = 0.f;
    else if (c < 4608) o[c] = vb[c - 3072];
}

// ---------------- LayerNorm (templated input dtype), bf16 output ----------------
template<typename TI>
__global__ __launch_bounds__(256) void ln_kernel(const TI* __restrict__ in, ushort* __restrict__ out,
                                                 const float* __restrict__ w, const float* __restrict__ b, int D){
    __shared__ float shs[4], shss[4];
    const int row = blockIdx.x;
    const TI* xr = in + (size_t)row * D;
    float s = 0.f, ss = 0.f;
    for (int i = threadIdx.x * 8; i < D; i += 2048){
        float vv[8];
        if constexpr (sizeof(TI) == 4){
            float4 a = *(const float4*)&xr[i];
            float4 c = *(const float4*)&xr[i + 4];
            vv[0]=a.x; vv[1]=a.y; vv[2]=a.z; vv[3]=a.w;
            vv[4]=c.x; vv[5]=c.y; vv[6]=c.z; vv[7]=c.w;
        } else {
            int4 u = *(const int4*)&xr[i];
            const ushort* up = (const ushort*)&u;
            #pragma unroll
            for (int j = 0; j < 8; ++j) vv[j] = bf2f(up[j]);
        }
        #pragma unroll
        for (int j = 0; j < 8; ++j){ s += vv[j]; ss += vv[j]*vv[j]; }
    }
    #pragma unroll
    for (int off = 32; off >= 1; off >>= 1){ s += __shfl_down(s, off); ss += __shfl_down(ss, off); }
    const int wid = threadIdx.x >> 6;
    if ((threadIdx.x & 63) == 0){ shs[wid] = s; shss[wid] = ss; }
    __syncthreads();
    s  = shs[0] + shs[1] + shs[2] + shs[3];
    ss = shss[0] + shss[1] + shss[2] + shss[3];
    const float mu  = s / D;
    const float inv = rsqrtf(ss / D - mu * mu + 1e-5f);
    ushort* orow = out + (size_t)row * D;
    for (int i = threadIdx.x * 8; i < D; i += 2048){
        float vv[8];
        if constexpr (sizeof(TI) == 4){
            float4 a = *(const float4*)&xr[i];
            float4 c = *(const float4*)&xr[i + 4];
            vv[0]=a.x; vv[1]=a.y; vv[2]=a.z; vv[3]=a.w;
            vv[4]=c.x; vv[5]=c.y; vv[6]=c.z; vv[7]=c.w;
        } else {
            int4 u = *(const int4*)&xr[i];
            const ushort* up = (const ushort*)&u;
            #pragma unroll
            for (int j = 0; j < 8; ++j) vv[j] = bf2f(up[j]);
        }
        ushort ov[8];
        #pragma unroll
        for (int j = 0; j < 8; ++j)
            ov[j] = f2bf((vv[j] - mu) * inv * w[i + j] + b[i + j]);
        *(int4*)&orow[i] = *(const int4*)ov;
    }
}

// ---------------- fused gate (a*b) + LayerNorm, bf16 in/out ----------------
__global__ __launch_bounds__(256) void lnmul_kernel(const ushort* __restrict__ ina, const ushort* __restrict__ inb,
                                                    ushort* __restrict__ out,
                                                    const float* __restrict__ w, const float* __restrict__ b, int D){
    __shared__ float shs[4], shss[4];
    const int row = blockIdx.x;
    const ushort* ar = ina + (size_t)row * D;
    const ushort* br = inb + (size_t)row * D;
    float s = 0.f, ss = 0.f;
    for (int i = threadIdx.x * 8; i < D; i += 2048){
        int4 ua = *(const int4*)&ar[i];
        int4 ub = *(const int4*)&br[i];
        const ushort* pa = (const ushort*)&ua;
        const ushort* pb = (const ushort*)&ub;
        #pragma unroll
        for (int j = 0; j < 8; ++j){ float v = bf2f(pa[j]) * bf2f(pb[j]); s += v; ss += v*v; }
    }
    #pragma unroll
    for (int off = 32; off >= 1; off >>= 1){ s += __shfl_down(s, off); ss += __shfl_down(ss, off); }
    const int wid = threadIdx.x >> 6;
    if ((threadIdx.x & 63) == 0){ shs[wid] = s; shss[wid] = ss; }
    __syncthreads();
    s  = shs[0] + shs[1] + shs[2] + shs[3];
    ss = shss[0] + shss[1] + shss[2] + shss[3];
    const float mu  = s / D;
    const float inv = rsqrtf(ss / D - mu * mu + 1e-5f);
    ushort* orow = out + (size_t)row * D;
    for (int i = threadIdx.x * 8; i < D; i += 2048){
        int4 ua = *(const int4*)&ar[i];
        int4 ub = *(const int4*)&br[i];
        const ushort* pa = (const ushort*)&ua;
        const ushort* pb = (const ushort*)&ub;
        ushort ov[8];
        #pragma unroll
        for (int j = 0; j < 8; ++j){
            float v = bf2f(pa[j]) * bf2f(pb[j]);
            ov[j] = f2bf((v - mu) * inv * w[i + j] + b[i + j]);
        }
        *(int4*)&orow[i] = *(const int4*)ov;
    }
}

// ---------------- bf16 MFMA GEMM with register-prefetch pipeline ----------------
// A[M][K] x Bt[N][K]^T -> C[M][N]
// epilogue: v=acc; (+bias[c_glob]); gelu?; (+bf16 addb); (*gvec[c_loc]); (+bf16 addb2); (+f32 addf)
// mode 0: single output C0 (row-major).
// mode 1: QKV 3-way split at col 1536 -> C0,C1,C2 in PERM layout [bt][h][n][64].
// mode 2: FFN pair split at col 6144 (C0 gelu'd, C1 plain; each N_out=6144, row-major).
__global__ __launch_bounds__(256) void mfma_gemm(
    const ushort* __restrict__ A, const ushort* __restrict__ Bt,
    int M, int N, int K,
    const float* __restrict__ bias, int dogelu,
    const ushort* __restrict__ addb, const float* __restrict__ gvec,
    const ushort* __restrict__ addb2, const float* __restrict__ addf,
    void* __restrict__ C0, void* __restrict__ C1, void* __restrict__ C2,
    int mode, int obf16)
{
    __shared__ ushort As[4096];   // 128 rows x 32 k, fragment-subtile order
    __shared__ ushort Bs[4096];
    const int tid  = threadIdx.x;
    const int lane = tid & 63, wv = tid >> 6;
    const int wr = wv >> 1, wc = wv & 1;
    const int row0 = blockIdx.y * 128, col0 = blockIdx.x * 128;

    const int crow = tid >> 2;          // 0..63
    const int ckb  = tid & 3;           // k-block of 8
    int ra0 = row0 + crow;       if (ra0 >= M) ra0 = M - 1;
    int ra1 = row0 + crow + 64;  if (ra1 >= M) ra1 = M - 1;
    const ushort* Ap0 = A  + (size_t)ra0 * K + ckb * 8;
    const ushort* Ap1 = A  + (size_t)ra1 * K + ckb * 8;
    const ushort* Bp0 = Bt + (size_t)(col0 + crow) * K + ckb * 8;
    const ushort* Bp1 = Bt + (size_t)(col0 + crow + 64) * K + ckb * 8;
    const int d0 = ((crow >> 4) << 9) + ((ckb << 4) + (crow & 15)) * 8;
    const int d1 = (((crow + 64) >> 4) << 9) + ((ckb << 4) + (crow & 15)) * 8;

    f32x4 acc[4][4] = {};
    const int nK = K >> 5;

    // prefetch step 0
    int4 a0 = *(const int4*)Ap0, a1 = *(const int4*)Ap1;
    int4 b0 = *(const int4*)Bp0, b1 = *(const int4*)Bp1;

    for (int ks = 0; ks < nK; ++ks){
        __syncthreads();
        *(int4*)&As[d0] = a0; *(int4*)&As[d1] = a1;
        *(int4*)&Bs[d0] = b0; *(int4*)&Bs[d1] = b1;
        __syncthreads();
        if (ks + 1 < nK){                 // issue next-step loads; latency hides under MFMA
            const int ko = (ks + 1) << 5;
            a0 = *(const int4*)(Ap0 + ko); a1 = *(const int4*)(Ap1 + ko);
            b0 = *(const int4*)(Bp0 + ko); b1 = *(const int4*)(Bp1 + ko);
        }
        bf16x8_t af[4], bfr[4];
        #pragma unroll
        for (int mi = 0; mi < 4; ++mi)
            af[mi] = *(const bf16x8_t*)&As[(((wr<<2)+mi) << 9) + lane * 8];
        #pragma unroll
        for (int ni = 0; ni < 4; ++ni)
            bfr[ni] = *(const bf16x8_t*)&Bs[(((wc<<2)+ni) << 9) + lane * 8];
        #pragma unroll
        for (int mi = 0; mi < 4; ++mi)
            #pragma unroll
            for (int ni = 0; ni < 4; ++ni)
                acc[mi][ni] = __builtin_amdgcn_mfma_f32_16x16x32_bf16(af[mi], bfr[ni], acc[mi][ni], 0, 0, 0);
    }

    // ---- output routing (block-uniform: 1536 and 6144 are multiples of 128) ----
    int cb = col0, Nout = N, gel = dogelu;
    void* Cp = C0;
    if (mode == 1){
        int seg = col0 / 1536;
        Cp = (seg == 0) ? C0 : ((seg == 1) ? C1 : C2);
        cb = col0 - seg * 1536; Nout = 1536;
    } else if (mode == 2){
        int seg = col0 / 6144;
        Cp = seg ? C1 : C0;
        cb = col0 - seg * 6144; Nout = 6144;
        if (seg) gel = 0;
    }

    const int fr = lane >> 4;   // 0..3
    const int fc = lane & 15;
    #pragma unroll
    for (int mi = 0; mi < 4; ++mi){
        #pragma unroll
        for (int j = 0; j < 4; ++j){
            const int r = row0 + wr*64 + mi*16 + fr*4 + j;
            if (r < M){
                #pragma unroll
                for (int ni = 0; ni < 4; ++ni){
                    const int cg = col0 + wc*64 + ni*16 + fc;          // global col (bias)
                    const int cl = cb   + wc*64 + ni*16 + fc;          // local col
                    float v = acc[mi][ni][j];
                    if (bias) v += bias[cg];
                    if (gel)  v = gelu_f(v);
                    if (addb)  v += bf2f(addb [(size_t)r*Nout + cl]);
                    if (gvec)  v *= gvec[cl];
                    if (addb2) v += bf2f(addb2[(size_t)r*Nout + cl]);
                    if (addf)  v += addf[(size_t)r*Nout + cl];
                    if (mode == 1){
                        // perm layout: [bt][h][n][64]
                        const int nt = r >> 6, btk = r & 63;
                        const int hh = cl >> 6, dd = cl & 63;
                        ((ushort*)Cp)[(((size_t)btk*HEADS + hh)*NTOK + nt)*HD + dd] = f2bf(v);
                    } else if (obf16) {
                        ((ushort*)Cp)[(size_t)r*Nout + cl] = f2bf(v);
                    } else {
                        ((float*) Cp)[(size_t)r*Nout + cl] = v;
                    }
                }
            }
        }
    }
}

// ---------------- temporal attention v2: perm-layout inputs, row-major output ----------------
__global__ __launch_bounds__(64) void attn_temporal_v2(
    const ushort* __restrict__ Qp, const ushort* __restrict__ Kp, const ushort* __restrict__ Vp,
    ushort* __restrict__ Ot)
{
    const int h = blockIdx.x, n = blockIdx.y, b = blockIdx.z;
    const int d = threadIdx.x;
    __shared__ float qs[8][64], ks[8][64], vs[8][64];
    __shared__ float sc[8][8], pr[8][8];
    #pragma unroll
    for (int t = 0; t < 8; ++t){
        size_t r = (((size_t)(b*8 + t)*HEADS + h)*NTOK + n)*HD + d;
        qs[t][d] = bf2f(Qp[r]); ks[t][d] = bf2f(Kp[r]); vs[t][d] = bf2f(Vp[r]);
    }
    __syncthreads();
    {
        const int qi = d >> 3, kj = d & 7;
        float s = 0.f;
        #pragma unroll
        for (int e = 0; e < 64; ++e) s = fmaf(qs[qi][e], ks[kj][e], s);
        sc[qi][kj] = s;
    }
    __syncthreads();
    if (d < 8){
        float m = -3.4e38f;
        #pragma unroll
        for (int j = 0; j < 8; ++j) m = fmaxf(m, sc[d][j]);
        float sum = 0.f;
        #pragma unroll
        for (int j = 0; j < 8; ++j){ float e = expf(sc[d][j] - m); pr[d][j] = e; sum += e; }
        const float inv = 1.f / sum;
        #pragma unroll
        for (int j = 0; j < 8; ++j) pr[d][j] *= inv;
    }
    __syncthreads();
    #pragma unroll
    for (int qi = 0; qi < 8; ++qi){
        float o = 0.f;
        #pragma unroll
        for (int t = 0; t < 8; ++t) o = fmaf(pr[qi][t], vs[t][d], o);
        Ot[((size_t)n*64 + b*8 + qi) * EMBED + h*64 + d] = f2bf(o);
    }
}

// ---------------- spatial attention v3: MFMA flash, perm inputs, row-major output ----------------
// grid (5 qtiles, 64 bt, 24 h); 256 threads = 4 waves, each wave owns 16 q-rows.
__global__ __launch_bounds__(256) void attn_spatial_v3(
    const ushort* __restrict__ Qp, const ushort* __restrict__ Kp, const ushort* __restrict__ Vp,
    const ushort* __restrict__ bias, ushort* __restrict__ Ot)
{
    const int qt = blockIdx.x, bt = blockIdx.y, h = blockIdx.z;
    const int lane = threadIdx.x & 63, w = threadIdx.x >> 6;
    const int fr = lane >> 4, fc = lane & 15;
    const size_t base = ((size_t)bt*HEADS + h) * (NTOK*HD);
    __shared__ ushort Pb[64 * 328];   // normalized P, bf16, stride 328
    __shared__ ushort Vt[64 * 72];    // V tile transposed [d][j], stride 72

    const int q0 = qt * 64;

    // ---- Q a-frags (wave's 16 q-rows) ----
    int qr = q0 + w*16 + fc; if (qr > 256) qr = 256;
    bf16x8_t aq0 = *(const bf16x8_t*)(Qp + base + (size_t)qr*HD + fr*8);
    bf16x8_t aq1 = *(const bf16x8_t*)(Qp + base + (size_t)qr*HD + 32 + fr*8);

    // ---- QK^T: 5 j-tiles, S kept in registers ----
    f32x4 sacc[5][4];
    #pragma unroll
    for (int t = 0; t < 5; ++t){
        #pragma unroll
        for (int jn = 0; jn < 4; ++jn){
            int jr = t*64 + jn*16 + fc; if (jr > 256) jr = 256;
            bf16x8_t b0 = *(const bf16x8_t*)(Kp + base + (size_t)jr*HD + fr*8);
            bf16x8_t b1 = *(const bf16x8_t*)(Kp + base + (size_t)jr*HD + 32 + fr*8);
            f32x4 a = {};
            a = __builtin_amdgcn_mfma_f32_16x16x32_bf16(aq0, b0, a, 0, 0, 0);
            a = __builtin_amdgcn_mfma_f32_16x16x32_bf16(aq1, b1, a, 0, 0, 0);
            sacc[t][jn] = a;
        }
    }

    // ---- bias + invalid-j mask + row max ----
    float m[4] = {-3.4e38f, -3.4e38f, -3.4e38f, -3.4e38f};
    #pragma unroll
    for (int jj = 0; jj < 4; ++jj){
        int n = q0 + w*16 + fr*4 + jj; if (n > 256) n = 256;
        const size_t brow = ((size_t)h*NTOK + n) * NTOK;
        #pragma unroll
        for (int t = 0; t < 5; ++t){
            #pragma unroll
            for (int jn = 0; jn < 4; ++jn){
                const int j = t*64 + jn*16 + fc;
                float s = sacc[t][jn][jj];
                if (j <= 256) s += bf2f(bias[brow + j]);
                else          s = -3.4e38f;
                sacc[t][jn][jj] = s;
                m[jj] = fmaxf(m[jj], s);
            }
        }
    }
    #pragma unroll
    for (int off = 1; off <= 8; off <<= 1){
        #pragma unroll
        for (int jj = 0; jj < 4; ++jj) m[jj] = fmaxf(m[jj], __shfl_xor(m[jj], off));
    }
    // ---- exp + row sum ----
    float sum[4] = {0.f, 0.f, 0.f, 0.f};
    #pragma unroll
    for (int t = 0; t < 5; ++t)
        #pragma unroll
        for (int jn = 0; jn < 4; ++jn)
            #pragma unroll
            for (int jj = 0; jj < 4; ++jj){
                float p = expf(sacc[t][jn][jj] - m[jj]);
                sacc[t][jn][jj] = p;
                sum[jj] += p;
            }
    #pragma unroll
    for (int off = 1; off <= 8; off <<= 1){
        #pragma unroll
        for (int jj = 0; jj < 4; ++jj) sum[jj] += __shfl_xor(sum[jj], off);
    }
    float inv[4];
    #pragma unroll
    for (int jj = 0; jj < 4; ++jj) inv[jj] = 1.f / sum[jj];

    // ---- write normalized P (bf16) to LDS ----
    #pragma unroll
    for (int t = 0; t < 5; ++t)
        #pragma unroll
        for (int jn = 0; jn < 4; ++jn)
            #pragma unroll
            for (int jj = 0; jj < 4; ++jj)
                Pb[(w*16 + fr*4 + jj) * 328 + t*64 + jn*16 + fc] = f2bf(sacc[t][jn][jj] * inv[jj]);

    // ---- PV: 5 V-tiles, V transposed through LDS ----
    f32x4 oacc[4] = {};
    for (int t = 0; t < 5; ++t){
        __syncthreads();   // previous tile's reads done; also makes Pb visible on t=0
        {
            const int j = threadIdx.x >> 2, ds0 = (threadIdx.x & 3) * 16;
            int jr = t*64 + j; if (jr > 256) jr = 256;
            const ushort* src = Vp + base + (size_t)jr*HD + ds0;
            ushort tmp[16];
            *(int4*)tmp       = *(const int4*)src;
            *(int4*)(tmp + 8) = *(const int4*)(src + 8);
            #pragma unroll
            for (int i = 0; i < 16; ++i) Vt[(ds0 + i)*72 + j] = tmp[i];
        }
        __syncthreads();
        #pragma unroll
        for (int kj = 0; kj < 2; ++kj){
            bf16x8_t ap = *(const bf16x8_t*)&Pb[(w*16 + fc) * 328 + t*64 + kj*32 + fr*8];
            #pragma unroll
            for (int dn = 0; dn < 4; ++dn){
                bf16x8_t bv = *(const bf16x8_t*)&Vt[(dn*16 + fc) * 72 + kj*32 + fr*8];
                oacc[dn] = __builtin_amdgcn_mfma_f32_16x16x32_bf16(ap, bv, oacc[dn], 0, 0, 0);
            }
        }
    }

    // ---- write O row-major ----
    #pragma unroll
    for (int jj = 0; jj < 4; ++jj){
        const int n = q0 + w*16 + fr*4 + jj;
        if (n <= 256){
            #pragma unroll
            for (int dn = 0; dn < 4; ++dn)
                Ot[((size_t)n*64 + bt) * EMBED + h*64 + dn*16 + fc] = f2bf(oacc[dn][jj]);
        }
    }
}

// ---------------- relative-position bias gather (bf16) ----------------
__global__ void bias_gather_kernel(const float* __restrict__ rpw, const int* __restrict__ bucket,
                                   ushort* __restrict__ bias){
    const int i = blockIdx.x * 256 + threadIdx.x;
    const int total = HEADS * NTOK * NTOK;
    if (i < total){
        const int h = i / (NTOK * NTOK);
        const int ij = i % (NTOK * NTOK);
        bias[i] = f2bf(rpw[(size_t)bucket[ij] * HEADS + h]);
    }
}

// ---------------- host-side helpers ----------------
static inline void g(const ushort* A, const ushort* Bt, int M, int N, int K,
                     const float* bias, int dogelu,
                     const ushort* addb, const float* gvec,
                     const ushort* addb2, const float* addf,
                     void* C0, void* C1, void* C2, int mode, int obf16, hipStream_t stream){
    dim3 grid(N / 128, (M + 127) / 128);
    mfma_gemm<<<grid, 256, 0, stream>>>(A, Bt, M, N, K, bias, dogelu, addb, gvec, addb2, addf,
                                        C0, C1, C2, mode, obf16);
}
static inline void tr(const float* w, ushort* wt, int K, int N, float sc, hipStream_t stream){
    transpose_w<<<dim3(N / 32, K / 32), 256, 0, stream>>>(w, wt, K, N, sc);
}

extern "C" void kernel_launch(void* const* d_in, const int* in_sizes, int n_in,
                              void* d_out, int out_size, void* d_ws, size_t ws_size,
                              hipStream_t stream){
    const float* x        = (const float*)d_in[0];
    const float* q_w      = (const float*)d_in[1];
    const float* k_w      = (const float*)d_in[2];
    const float* v_w      = (const float*)d_in[3];
    const float* out_w    = (const float*)d_in[4];
    const float* q_b      = (const float*)d_in[5];
    const float* v_b      = (const float*)d_in[6];
    const float* out_b    = (const float*)d_in[7];
    const float* attn_ln_w= (const float*)d_in[8];
    const float* attn_ln_b= (const float*)d_in[9];
    const float* sa_ln_w  = (const float*)d_in[10];
    const float* sa_ln_b  = (const float*)d_in[11];
    const float* fin_ln_w = (const float*)d_in[12];
    const float* fin_ln_b = (const float*)d_in[13];
    const float* wi0      = (const float*)d_in[14];
    const float* wi1      = (const float*)d_in[15];
    const float* ffn_ln_w = (const float*)d_in[16];
    const float* ffn_ln_b = (const float*)d_in[17];
    const float* ffn_out_w= (const float*)d_in[18];
    const float* ffn_out_b= (const float*)d_in[19];
    const float* gamma1   = (const float*)d_in[20];
    const float* gamma2   = (const float*)d_in[21];
    const float* t_fc1_w  = (const float*)d_in[22];
    const float* t_fc1_b  = (const float*)d_in[23];
    const float* t_fc2_w  = (const float*)d_in[24];
    const float* t_fc2_b  = (const float*)d_in[25];
    const float* s_fc1_w  = (const float*)d_in[26];
    const float* s_fc1_b  = (const float*)d_in[27];
    const float* s_fc2_w  = (const float*)d_in[28];
    const float* s_fc2_b  = (const float*)d_in[29];
    const float* m_fc1_w  = (const float*)d_in[30];
    const float* m_fc1_b  = (const float*)d_in[31];
    const float* m_fc2_w  = (const float*)d_in[32];
    const float* m_fc2_b  = (const float*)d_in[33];
    const float* rel_pos_w= (const float*)d_in[34];
    const int*   rp_bucket= (const int*)d_in[35];

    const size_t TOKD  = (size_t)TOK * EMBED;          // 25,264,128
    const size_t BIASZ = (size_t)HEADS * NTOK * NTOK;  //  1,585,176

    ushort* ws = (ushort*)d_ws;
    size_t off = 0;
    auto carve = [&](size_t n){ ushort* p = ws + off; off += n; return p; };

    // bf16-transposed weights
    ushort* WQKV = carve((size_t)4608 * EMBED);        // [Q|K|V] rows, Q pre-scaled by 0.125
    ushort* WTO  = carve((size_t)EMBED * EMBED);
    ushort* WI01 = carve((size_t)2 * FFN * EMBED);     // [wi0 | wi1] rows
    ushort* WTFO = carve((size_t)EMBED * FFN);
    ushort* WTT1 = carve((size_t)DA * EMBED);
    ushort* WTT2 = carve((size_t)EMBED * DA);
    ushort* WTS1 = carve((size_t)DA * EMBED);
    ushort* WTS2 = carve((size_t)EMBED * DA);
    ushort* WTM1 = carve((size_t)DA * EMBED);
    ushort* WTM2 = carve((size_t)EMBED * DA);
    // token-sized bf16 buffers (2 in ws; 2 more live in d_out)
    ushort* W0   = carve(TOKD);
    ushort* W1   = carve(TOKD);
    ushort* BIAS = carve(BIASZ);
    float*  B4608= (float*)carve(9216);                // 4608 fp32
    // scratch union: adapter-hidden full vs H0|H1 (ffn chunk loop)
    const size_t s_ab = (size_t)TOK * DA;              //  6,316,032
    const size_t s_h  = (size_t)2 * CHF * FFN;         // 18,874,368
    ushort* SCR = carve(s_h > s_ab ? s_h : s_ab);
    ushort* AB  = SCR;                                 // TOK x DA
    ushort* H0  = SCR;                                 // CHF x FFN
    ushort* H1  = SCR + (size_t)CHF * FFN;

    const size_t need = off * sizeof(ushort);
    if (ws_size < need) return;   // diagnostic: zero output => ws too small

    // d_out hosts two bf16 token buffers; final fp32 result overwrites both
    ushort* DL = (ushort*)d_out;          // low half
    ushort* DH = (ushort*)d_out + TOKD;   // high half
    float*  out = (float*)d_out;

    // ---------------- weight prep ----------------
    tr(q_w,   WQKV,                      EMBED, EMBED, 0.125f, stream);
    tr(k_w,   WQKV + (size_t)1536*EMBED, EMBED, EMBED, 1.f, stream);
    tr(v_w,   WQKV + (size_t)3072*EMBED, EMBED, EMBED, 1.f, stream);
    tr(out_w, WTO,  EMBED, EMBED, 1.f, stream);
    tr(wi0,   WI01,                     EMBED, FFN, 1.f, stream);
    tr(wi1,   WI01 + (size_t)FFN*EMBED, EMBED, FFN, 1.f, stream);
    tr(ffn_out_w, WTFO, FFN, EMBED, 1.f, stream);
    tr(t_fc1_w, WTT1, EMBED, DA, 1.f, stream);
    tr(t_fc2_w, WTT2, DA, EMBED, 1.f, stream);
    tr(s_fc1_w, WTS1, EMBED, DA, 1.f, stream);
    tr(s_fc2_w, WTS2, DA, EMBED, 1.f, stream);
    tr(m_fc1_w, WTM1, EMBED, DA, 1.f, stream);
    tr(m_fc2_w, WTM2, DA, EMBED, 1.f, stream);
    build_qkv_bias<<<18, 256, 0, stream>>>(q_b, v_b, B4608);
    bias_gather_kernel<<<(HEADS*NTOK*NTOK + 255)/256, 256, 0, stream>>>(rel_pos_w, rp_bucket, BIAS);

    // ================= temporal attention =================
    ln_kernel<float><<<TOK, 256, 0, stream>>>(x, DH, sa_ln_w, sa_ln_b, EMBED);
    g(DH, WQKV, TOK, 4608, EMBED, B4608, 0, nullptr, nullptr, nullptr, nullptr,
      W0, W1, DL, 1, 1, stream);                                      // perm: Q->W0 K->W1 V->DL
    attn_temporal_v2<<<dim3(HEADS, NTOK, BV), 64, 0, stream>>>(W0, W1, DL, DH);  // At -> DH (row-major)
    ln_kernel<ushort><<<TOK, 256, 0, stream>>>(DH, W0, attn_ln_w, attn_ln_b, EMBED);
    g(W0, WTO, TOK, EMBED, EMBED, out_b, 0, nullptr, nullptr, nullptr, nullptr,
      W1, nullptr, nullptr, 0, 1, stream);                            // AO -> W1
    g(W1, WTT1, TOK, DA, EMBED, t_fc1_b, 1, nullptr, nullptr, nullptr, nullptr,
      AB, nullptr, nullptr, 0, 1, stream);
    g(AB, WTT2, TOK, EMBED, DA, t_fc2_b, 0, nullptr, nullptr, nullptr, x,
      DL, nullptr, nullptr, 0, 1, stream);                            // x1 = x + adapt_t -> DL

    // ================= spatial attention =================
    ln_kernel<ushort><<<TOK, 256, 0, stream>>>(DL, DH, sa_ln_w, sa_ln_b, EMBED);
    g(DH, WQKV, TOK, 4608, EMBED, B4608, 0, nullptr, nullptr, nullptr, nullptr,
      W0, W1, DL, 1, 1, stream);                                      // perm: Q->W0 K->W1 V->DL
    attn_spatial_v3<<<dim3(5, BT, HEADS), 256, 0, stream>>>(W0, W1, DL, BIAS, DH);  // O -> DH
    ln_kernel<ushort><<<TOK, 256, 0, stream>>>(DH, W0, attn_ln_w, attn_ln_b, EMBED);
    g(W0, WTO, TOK, EMBED, EMBED, out_b, 0, nullptr, nullptr, nullptr, nullptr,
      W1, nullptr, nullptr, 0, 1, stream);                            // aos -> W1
    g(W1, WTS1, TOK, DA, EMBED, s_fc1_b, 1, nullptr, nullptr, nullptr, nullptr,
      AB, nullptr, nullptr, 0, 1, stream);
    // x2 = x + gamma1*(aos + acc + s_fc2_b)  -> DL (bf16)
    g(AB, WTS2, TOK, EMBED, DA, s_fc2_b, 0, W1, gamma1, nullptr, x,
      DL, nullptr, nullptr, 0, 1, stream);

    // ================= FFN (GEGLU + inner LN) + adapter m + final combine =================
    ln_kernel<ushort><<<TOK, 256, 0, stream>>>(DL, DH, fin_ln_w, fin_ln_b, EMBED);   // xn -> DH
    g(DH, WTM1, TOK, DA, EMBED, m_fc1_b, 1, nullptr, nullptr, nullptr, nullptr,
      AB, nullptr, nullptr, 0, 1, stream);
    // Madd = x2 + adapter_m -> W0 (bf16)
    g(AB, WTM2, TOK, EMBED, DA, m_fc2_b, 0, DL, nullptr, nullptr, nullptr,
      W0, nullptr, nullptr, 0, 1, stream);
    for (int m0 = 0; m0 < TOK; m0 += CHF){
        const int mc = (TOK - m0 < CHF) ? (TOK - m0) : CHF;
        // H0 = gelu(xn@wi0), H1 = xn@wi1  (merged, N=12288)
        g(DH + (size_t)m0*EMBED, WI01, mc, 2*FFN, EMBED, nullptr, 2, nullptr, nullptr, nullptr, nullptr,
          H0, H1, nullptr, 2, 1, stream);
        lnmul_kernel<<<mc, 256, 0, stream>>>(H0, H1, H0, ffn_ln_w, ffn_ln_b, FFN);
        // out = gamma2*(acc + ffn_out_b) + Madd   (fp32 -> d_out)
        g(H0, WTFO, mc, EMBED, FFN, ffn_out_b, 0, nullptr, gamma2, W0 + (size_t)m0*EMBED, nullptr,
          out + (size_t)m0*EMBED, nullptr, nullptr, 0, 0, stream);
    }
}